// Round 1
// baseline (20553.987 us; speedup 1.0000x reference)
//
#include <hip/hip_runtime.h>

// Problem constants
#define NN 256
#define HD 128
#define MLPH 256

// ws layout (floats):
//   Hs   : [0,      32768)   current hidden state [256][128]
//   H1   : [32768,  65536)   layer-1 temp         [256][128]
//   cp   : [65536,  131072)  pos_emb[t] @ Wm1_p   [256][256]
//   cz   : [131072, 131328)  bm1 + z @ Wm1_z      [256]
//   ancT : [131328, 133376)  ancestor bitmask, transposed: ancT[i] word w bit b == anc[32w+b][i]
#define HS_OFF  0
#define H1_OFF  32768
#define CP_OFF  65536
#define CZ_OFF  131072
#define ANC_OFF 131328

__global__ void k_init(const float* __restrict__ z, const int* __restrict__ targets,
                       const float* __restrict__ pos_emb, const float* __restrict__ Wm1,
                       const float* __restrict__ bm1, float* __restrict__ ws,
                       float* __restrict__ out)
{
    int b = blockIdx.x, tid = threadIdx.x;
    float* Hs = ws + HS_OFF;
    float* cp = ws + CP_OFF;
    float* cz = ws + CZ_OFF;
    unsigned* ancT = (unsigned*)(ws + ANC_OFF);
    if (b < NN) {
        int c = tid;
        // output 0: tgt = tril(targets, -1)
        out[b * NN + c] = (c < b) ? (float)targets[b * NN + c] : 0.0f;
        // cp[b][c] = sum_k pos_emb[b][k] * Wm1[384+k][c]
        float acc = 0.0f;
        for (int k = 0; k < HD; ++k)
            acc += pos_emb[b * HD + k] * Wm1[(384 + k) * MLPH + c];
        cp[b * MLPH + c] = acc;
        if (tid < HD) Hs[b * HD + tid] = (b == 0) ? z[tid] : 0.0f;  // H0 row0 = z (no pos_emb!)
        if (tid < 8) ancT[b * 8 + tid] = 0u;
    } else {
        int c = tid;
        float acc = bm1[c];
        for (int k = 0; k < HD; ++k)
            acc += z[k] * Wm1[(256 + k) * MLPH + c];
        cz[c] = acc;
        if (tid == 0) out[NN * NN + NN * 16] = 0.0f;  // lp accumulator
    }
}

// One GNN layer: dst[i] = relu(src_i @ Ws + m_i @ Wn + b) for i = 0..rmax
//   m_i = sum_{j<i} tgt[i][j] * src[j]  if i < tgate, else 0
//   src_i = z + pos_emb[i]  if i == tnew (new node this step), else src[i]
__global__ void k_layer(const float* __restrict__ src, float* __restrict__ dst,
                        const float* __restrict__ Ws, const float* __restrict__ Wn,
                        const float* __restrict__ bias, const int* __restrict__ targets,
                        const float* __restrict__ z, const float* __restrict__ pos_emb,
                        int rmax, int tgate, int tnew)
{
    __shared__ float sh[4][256];  // per wave: [0:128) h, [128:256) m
    int tid = threadIdx.x, lane = tid & 63, wv = tid >> 6;
    int i = blockIdx.x * 4 + wv;
    if (i > rmax) return;  // no __syncthreads in this kernel

    const float2* s2 = (const float2*)src;
    float2 m = make_float2(0.0f, 0.0f);
    int jmax = (i < tgate) ? i : 0;
    const int* trow = targets + i * NN;
    for (int j = 0; j < jmax; ++j) {
        if (trow[j] != 0) {  // wave-uniform branch; tgt entries are 0/1
            float2 v = s2[j * 64 + lane];
            m.x += v.x; m.y += v.y;
        }
    }
    float2 h;
    if (i == tnew) {
        h.x = z[2 * lane]     + pos_emb[i * HD + 2 * lane];
        h.y = z[2 * lane + 1] + pos_emb[i * HD + 2 * lane + 1];
    } else {
        h = s2[i * 64 + lane];
    }
    sh[wv][2 * lane] = h.x;       sh[wv][2 * lane + 1] = h.y;
    sh[wv][128 + 2 * lane] = m.x; sh[wv][128 + 2 * lane + 1] = m.y;
    __threadfence_block();  // lgkmcnt(0): cross-lane LDS visibility within the wave

    float2 acc = ((const float2*)bias)[lane];
    const float2* W1 = (const float2*)Ws;
    const float2* W2 = (const float2*)Wn;
#pragma unroll 4
    for (int k = 0; k < HD; ++k) {
        float hk = sh[wv][k], mk = sh[wv][128 + k];
        float2 a = W1[k * 64 + lane];
        float2 bb = W2[k * 64 + lane];
        acc.x += hk * a.x + mk * bb.x;
        acc.y += hk * a.y + mk * bb.y;
    }
    acc.x = fmaxf(acc.x, 0.0f);
    acc.y = fmaxf(acc.y, 0.0f);
    ((float2*)dst)[i * 64 + lane] = acc;
}

// Per-step MLP + logp + ancestor update. One wave per candidate row i < t.
__global__ void k_mlp(const float* __restrict__ Hs, const float* __restrict__ Wm1,
                      const float* __restrict__ Wm2, const float* __restrict__ bm2,
                      const int* __restrict__ targets, float* __restrict__ ws,
                      float* __restrict__ lp_out, int t)
{
    __shared__ float ct[MLPH];
    __shared__ unsigned gtm[8];
    __shared__ float hrow[4][HD];
    __shared__ float lpacc;
    const float* cp = ws + CP_OFF;
    const float* cz = ws + CZ_OFF;
    unsigned* ancT = (unsigned*)(ws + ANC_OFF);
    int tid = threadIdx.x, lane = tid & 63, wv = tid >> 6;

    // phase a (whole block): ct[c] = bm1+cz + cp[t] + h_t @ Wm1_top ; gt bitmask of row t
    {
        int c = tid;
        float acc = cz[c] + cp[t * MLPH + c];
        const float* ht = Hs + t * HD;
        for (int k = 0; k < HD; ++k)
            acc += ht[k] * Wm1[k * MLPH + c];
        ct[c] = acc;
    }
    if (tid < 8) {
        unsigned mask = 0;
        const int* trow = targets + t * NN;
        int base = tid * 32;
        for (int b = 0; b < 32; ++b) {
            int j = base + b;
            if (j < t && trow[j] != 0) mask |= (1u << b);
        }
        gtm[tid] = mask;
    }
    if (tid == 0) lpacc = 0.0f;
    __syncthreads();

    int i = blockIdx.x * 4 + wv;
    float lpv = 0.0f;
    if (i < t) {
        const float2* s2 = (const float2*)Hs;
        float2 hv = s2[i * 64 + lane];
        hrow[wv][2 * lane] = hv.x; hrow[wv][2 * lane + 1] = hv.y;
        __threadfence_block();
        float4 a = make_float4(0.0f, 0.0f, 0.0f, 0.0f);
        const float4* W = (const float4*)(Wm1 + HD * MLPH);  // rows 128..255 (Hs block)
        for (int k = 0; k < HD; ++k) {
            float hk = hrow[wv][k];
            float4 w = W[k * 64 + lane];
            a.x += hk * w.x; a.y += hk * w.y; a.z += hk * w.z; a.w += hk * w.w;
        }
        float4 cc = ((const float4*)ct)[lane];
        float4 w2 = ((const float4*)Wm2)[lane];
        float s = fmaxf(a.x + cc.x, 0.0f) * w2.x
                + fmaxf(a.y + cc.y, 0.0f) * w2.y
                + fmaxf(a.z + cc.z, 0.0f) * w2.z
                + fmaxf(a.w + cc.w, 0.0f) * w2.w;
        for (int off = 32; off > 0; off >>= 1) s += __shfl_xor(s, off, 64);
        if (lane == 0) {
            float logit = s + bm2[0];
            float prob = 1.0f / (1.0f + expf(-logit));
            unsigned cnt = 0, has = 0;
            for (int w = 0; w < 8; ++w) {
                unsigned av = ancT[i * 8 + w];
                cnt += __popc(av);
                has |= av & gtm[w];
            }
            float supp = ldexpf(1.0f, -(int)cnt);  // (1-0.5)^cnt, exact incl. underflow
            float adj = prob * supp;
            unsigned gt = (gtm[i >> 5] >> (i & 31)) & 1u;
            lpv = gt ? logf(adj + 1e-12f) : logf(1.0f - adj + 1e-12f);
            unsigned ab = (has != 0u) | gt;  // anc[t][i] = OR_p(gt[p]&anc[p][i]) | gt[i]
            if (ab) ancT[i * 8 + (t >> 5)] |= (1u << (t & 31));
        }
    }
    if (lane == 0 && lpv != 0.0f) atomicAdd(&lpacc, lpv);
    __syncthreads();
    if (tid == 0 && lpacc != 0.0f) atomicAdd(lp_out, lpacc);
}

__global__ void k_xout(const float* __restrict__ Hs, const float* __restrict__ Wf,
                       const float* __restrict__ bf, float* __restrict__ out)
{
    int tid = threadIdx.x;
    int i = blockIdx.x * 16 + (tid >> 4);
    int f = tid & 15;
    float acc = bf[f];
    for (int k = 0; k < HD; ++k)
        acc += Hs[i * HD + k] * Wf[k * 16 + f];
    out[NN * NN + i * 16 + f] = acc;
}

extern "C" void kernel_launch(void* const* d_in, const int* in_sizes, int n_in,
                              void* d_out, int out_size, void* d_ws, size_t ws_size,
                              hipStream_t stream)
{
    const float* z       = (const float*)d_in[0];
    const int*   targets = (const int*)d_in[1];
    const float* pos_emb = (const float*)d_in[2];
    const float* Ws1     = (const float*)d_in[3];
    const float* Wn1     = (const float*)d_in[4];
    const float* b1      = (const float*)d_in[5];
    const float* Ws2     = (const float*)d_in[6];
    const float* Wn2     = (const float*)d_in[7];
    const float* b2      = (const float*)d_in[8];
    const float* Wm1     = (const float*)d_in[9];
    const float* bm1     = (const float*)d_in[10];
    const float* Wm2     = (const float*)d_in[11];
    const float* bm2     = (const float*)d_in[12];
    const float* Wf      = (const float*)d_in[13];
    const float* bf      = (const float*)d_in[14];
    float* out = (float*)d_out;
    float* ws  = (float*)d_ws;
    float* Hs = ws + HS_OFF;
    float* H1 = ws + H1_OFF;
    float* lp = out + NN * NN + NN * 16;

    k_init<<<dim3(NN + 1), dim3(256), 0, stream>>>(z, targets, pos_emb, Wm1, bm1, ws, out);

    for (int t = 1; t < NN; ++t) {
        int blocks = (t + 1 + 3) / 4;  // rows 0..t, one wave per row
        k_layer<<<dim3(blocks), dim3(256), 0, stream>>>(Hs, H1, Ws1, Wn1, b1, targets,
                                                        z, pos_emb, t, t, t);
        k_layer<<<dim3(blocks), dim3(256), 0, stream>>>(H1, Hs, Ws2, Wn2, b2, targets,
                                                        z, pos_emb, t, t, -1);
        k_mlp<<<dim3((t + 3) / 4), dim3(256), 0, stream>>>(Hs, Wm1, Wm2, bm2, targets,
                                                           ws, lp, t);
    }
    // final full-graph GNN pass (M = full tgt, all rows active)
    k_layer<<<dim3(64), dim3(256), 0, stream>>>(Hs, H1, Ws1, Wn1, b1, targets,
                                                z, pos_emb, NN - 1, NN, -1);
    k_layer<<<dim3(64), dim3(256), 0, stream>>>(H1, Hs, Ws2, Wn2, b2, targets,
                                                z, pos_emb, NN - 1, NN, -1);
    k_xout<<<dim3(16), dim3(256), 0, stream>>>(Hs, Wf, bf, out);
}

// Round 2
// 10421.664 us; speedup vs baseline: 1.9722x; 1.9722x over previous
//
#include <hip/hip_runtime.h>

#define NN 256
#define HD 128
#define NBLK 193

// ws float offsets
#define HS0_OFF   0
#define HS1_OFF   32768
#define H1_OFF    65536
#define CZ_OFF    98304
#define CT_OFF    98560
#define ANC_OFF   98816   // 2048 u32 (256 rows x 8 words), ancT[i] bit j == anc[j][i]
#define TGTM_OFF  100864  // 2048 u32 (256 rows x 8 words), bitmask of tril(targets,-1)
#define BAR_OFF   102912  // 4 u32: [0]=count, [1]=generation

// LDS float offsets (one 139 KiB array, layout per block-group)
#define ST_LDS 32768   // G1/G2: per-wave h/m staging, wv*256
#define W2_LDS 32768   // G3: Wm2 [32768,33024)
#define HR_LDS 33024   // G3: per-wave h row, wv*128
#define GT_LDS 33536   // G3: 8 u32 gt row mask
#define LP_LDS 33544   // G3: block lp accumulator
#define HS_LDS 32768   // G4: h row [32768,32896), pos row [32896,33024)

__device__ __forceinline__ void gridbar(unsigned* bar) {
    __syncthreads();
    if (threadIdx.x == 0) {
        __threadfence();  // release this block's writes (agent scope, incl. L2 wb)
        unsigned g = __hip_atomic_load(bar + 1, __ATOMIC_RELAXED, __HIP_MEMORY_SCOPE_AGENT);
        unsigned a = __hip_atomic_fetch_add(bar, 1u, __ATOMIC_ACQ_REL, __HIP_MEMORY_SCOPE_AGENT);
        if (a == (unsigned)(NBLK - 1)) {
            __hip_atomic_store(bar, 0u, __ATOMIC_RELAXED, __HIP_MEMORY_SCOPE_AGENT);
            __hip_atomic_fetch_add(bar + 1, 1u, __ATOMIC_RELEASE, __HIP_MEMORY_SCOPE_AGENT);
        } else {
            while (__hip_atomic_load(bar + 1, __ATOMIC_RELAXED, __HIP_MEMORY_SCOPE_AGENT) == g)
                __builtin_amdgcn_s_sleep(2);
        }
        __threadfence();  // acquire: invalidate caches so we see others' writes
    }
    __syncthreads();
}

// One GNN layer row: dst[r] = relu(src_r @ Ws + m_r @ Wn + b), one wave per row.
// Ws in lds[0,16384), Wn in lds[16384,32768).
__device__ __forceinline__ void layer_rows(const float* __restrict__ src, float* __restrict__ dst,
    const float* __restrict__ bias, const float* __restrict__ z, const float* __restrict__ pos_emb,
    const unsigned* __restrict__ tgtm, float* lds, int gblk, int rmax, int tgate, int tnew)
{
    const int tid = threadIdx.x, lane = tid & 63, wv = tid >> 6;
    const int r = gblk * 4 + wv;
    if (r > rmax) return;  // no syncthreads below
    const float2* s2 = (const float2*)src;
    float2 m = make_float2(0.f, 0.f);
    const int jm = (r < tgate) ? r : 0;  // edges j<r only if row gated active
    const unsigned* tg = tgtm + r * 8;
    const int nw = (jm + 31) >> 5;
    for (int w = 0; w < nw; ++w) {
        unsigned mask = tg[w];
        const int rem = jm - w * 32;
        if (rem < 32) mask &= (rem <= 0) ? 0u : ((1u << rem) - 1u);
        if (mask) {
            const float2* p = s2 + w * 32 * 64 + lane;
#pragma unroll
            for (int bb = 0; bb < 32; ++bb) {  // unconditional loads -> deep pipelining
                float2 v = p[bb * 64];
                float sel = (float)((mask >> bb) & 1u);
                m.x = fmaf(sel, v.x, m.x);
                m.y = fmaf(sel, v.y, m.y);
            }
        }
    }
    float2 h;
    if (r == tnew) {
        h.x = z[2 * lane]     + pos_emb[r * HD + 2 * lane];
        h.y = z[2 * lane + 1] + pos_emb[r * HD + 2 * lane + 1];
    } else {
        h = s2[r * 64 + lane];
    }
    float* st = lds + ST_LDS + wv * 256;
    st[2 * lane] = h.x;       st[2 * lane + 1] = h.y;
    st[128 + 2 * lane] = m.x; st[129 + 2 * lane] = m.y;
    __threadfence_block();
    float2 acc = ((const float2*)bias)[lane];
#pragma unroll 4
    for (int k = 0; k < HD; ++k) {
        const float hk = st[k], mk = st[128 + k];
        const float2 w1 = *(const float2*)(lds + k * HD + 2 * lane);
        const float2 w2 = *(const float2*)(lds + 16384 + k * HD + 2 * lane);
        acc.x = fmaf(hk, w1.x, fmaf(mk, w2.x, acc.x));
        acc.y = fmaf(hk, w1.y, fmaf(mk, w2.y, acc.y));
    }
    acc.x = fmaxf(acc.x, 0.f);
    acc.y = fmaxf(acc.y, 0.f);
    ((float2*)dst)[r * 64 + lane] = acc;
}

// G4: ct[c] = cz[c] + pos_emb[s]@Wm1_pos[:,c] + Hs_s[s]@Wm1_top[:,c]. Wm1_top in LDS.
__device__ __forceinline__ void ct_calc(const float* __restrict__ hsP, const float* __restrict__ pos_emb,
    const float* __restrict__ Wm1, const float* __restrict__ cz, float* __restrict__ ct,
    float* lds, int s)
{
    const int tid = threadIdx.x;
    if (tid < 128) lds[HS_LDS + tid] = hsP[s * HD + tid];
    else           lds[HS_LDS + tid] = pos_emb[s * HD + (tid - 128)];
    __syncthreads();
    float acc = cz[tid];
    const float* wp = Wm1 + 384 * 256 + tid;
#pragma unroll 4
    for (int k = 0; k < HD; ++k) {
        acc = fmaf(lds[HS_LDS + k], lds[k * 256 + tid], acc);
        acc = fmaf(lds[HS_LDS + 128 + k], wp[k * 256], acc);
    }
    ct[tid] = acc;
}

// G3: MLP for candidates i < s, plus logp + ancestor-bitmask update. Wm1_mid in LDS.
__device__ __forceinline__ void mlp_step(const float* __restrict__ hsS, const float* __restrict__ ct,
    const float* __restrict__ bm2, unsigned* __restrict__ ancT, const unsigned* __restrict__ tgtm,
    float* __restrict__ lp_out, float* lds, int gblk, int s)
{
    const int tid = threadIdx.x, lane = tid & 63, wv = tid >> 6;
    unsigned* gtl = (unsigned*)(lds + GT_LDS);
    if (tid < 8) gtl[tid] = tgtm[s * 8 + tid];
    if (tid == 0) lds[LP_LDS] = 0.0f;
    __syncthreads();
    const int i = gblk * 4 + wv;
    if (i < s) {
        const float2* s2 = (const float2*)hsS;
        float2 hv = s2[i * 64 + lane];
        float* hr = lds + HR_LDS + wv * 128;
        hr[2 * lane] = hv.x; hr[2 * lane + 1] = hv.y;
        __threadfence_block();
        float4 a = make_float4(0.f, 0.f, 0.f, 0.f);
#pragma unroll 4
        for (int k = 0; k < HD; ++k) {
            const float hk = hr[k];
            const float4 w = *(const float4*)(lds + k * 256 + 4 * lane);
            a.x = fmaf(hk, w.x, a.x); a.y = fmaf(hk, w.y, a.y);
            a.z = fmaf(hk, w.z, a.z); a.w = fmaf(hk, w.w, a.w);
        }
        const float4 cc = *(const float4*)(ct + 4 * lane);
        const float4 w2 = *(const float4*)(lds + W2_LDS + 4 * lane);
        float sd = fmaxf(a.x + cc.x, 0.f) * w2.x
                 + fmaxf(a.y + cc.y, 0.f) * w2.y
                 + fmaxf(a.z + cc.z, 0.f) * w2.z
                 + fmaxf(a.w + cc.w, 0.f) * w2.w;
#pragma unroll
        for (int off = 32; off > 0; off >>= 1) sd += __shfl_xor(sd, off);
        if (lane == 0) {
            const float logit = sd + bm2[0];
            const float prob = 1.0f / (1.0f + expf(-logit));
            const uint4* ap = (const uint4*)(ancT + i * 8);
            const uint4 a0 = ap[0], a1 = ap[1];
            unsigned cnt = __popc(a0.x) + __popc(a0.y) + __popc(a0.z) + __popc(a0.w)
                         + __popc(a1.x) + __popc(a1.y) + __popc(a1.z) + __popc(a1.w);
            unsigned has = (a0.x & gtl[0]) | (a0.y & gtl[1]) | (a0.z & gtl[2]) | (a0.w & gtl[3])
                         | (a1.x & gtl[4]) | (a1.y & gtl[5]) | (a1.z & gtl[6]) | (a1.w & gtl[7]);
            const float supp = ldexpf(1.0f, -(int)cnt);  // 0.5^cnt exact
            const float adj = prob * supp;
            const unsigned gt = (gtl[i >> 5] >> (i & 31)) & 1u;
            const float lpv = gt ? logf(adj + 1e-12f) : logf(1.0f - adj + 1e-12f);
            atomicAdd((float*)(lds + LP_LDS), lpv);
            if (has | gt) ancT[i * 8 + (s >> 5)] |= (1u << (s & 31));  // anc[s][i]
        }
    }
    __syncthreads();
    if (tid == 0) {
        const float v = lds[LP_LDS];
        if (v != 0.0f) atomicAdd(lp_out, v);
    }
}

extern "C" __global__ void __launch_bounds__(256)
fused_gnn(const float* z, const int* targets, const float* pos_emb,
          const float* Ws1, const float* Wn1, const float* b1,
          const float* Ws2, const float* Wn2, const float* b2,
          const float* Wm1, const float* bm1, const float* Wm2, const float* bm2,
          const float* Wf, const float* bf, float* out, float* ws)
{
    __shared__ __align__(16) float lds[34816];
    const int b = blockIdx.x;
    const int tid = threadIdx.x, lane = tid & 63, wv = tid >> 6;

    float* h1w = ws + H1_OFF;
    float* czw = ws + CZ_OFF;
    float* ctw = ws + CT_OFF;
    unsigned* ancw = (unsigned*)(ws + ANC_OFF);
    unsigned* tgtm = (unsigned*)(ws + TGTM_OFF);
    unsigned* bar  = (unsigned*)(ws + BAR_OFF);
    float* lp_out = out + NN * NN + NN * 16;

    // ---- LDS weight staging (per group) ----
    {
        const float* w0; const float* w1;
        if (b < 64)       { w0 = Ws1;             w1 = Wn1; }
        else if (b < 128) { w0 = Ws2;             w1 = Wn2; }
        else if (b < 192) { w0 = Wm1 + 128 * 256; w1 = Wm1 + 128 * 256 + 16384; }  // Wm1_mid
        else              { w0 = Wm1;             w1 = Wm1 + 16384; }              // Wm1_top
        float4* l4 = (float4*)lds;
        const float4* a4 = (const float4*)w0;
        const float4* b4 = (const float4*)w1;
#pragma unroll
        for (int i2 = 0; i2 < 16; ++i2) l4[tid + i2 * 256] = a4[tid + i2 * 256];
#pragma unroll
        for (int i2 = 0; i2 < 16; ++i2) l4[4096 + tid + i2 * 256] = b4[tid + i2 * 256];
        if (b >= 128 && b < 192 && tid < 64)
            ((float4*)(lds + W2_LDS))[tid] = ((const float4*)Wm2)[tid];
    }

    // ---- global init (split across blocks) ----
    if (b < 64) {
        const int r = b * 4 + wv;
        const int4 tv = ((const int4*)(targets + r * NN))[lane];
        float4 ov;
        ov.x = (4 * lane     < r) ? (float)tv.x : 0.f;
        ov.y = (4 * lane + 1 < r) ? (float)tv.y : 0.f;
        ov.z = (4 * lane + 2 < r) ? (float)tv.z : 0.f;
        ov.w = (4 * lane + 3 < r) ? (float)tv.w : 0.f;
        ((float4*)(out + r * NN))[lane] = ov;  // output 0: tgt
#pragma unroll
        for (int q = 0; q < 4; ++q) {
            const int j = q * 64 + lane;
            unsigned long long bbm = __ballot(j < r && targets[r * NN + j] != 0);
            if (lane == 0) {
                tgtm[r * 8 + 2 * q]     = (unsigned)bbm;
                tgtm[r * 8 + 2 * q + 1] = (unsigned)(bbm >> 32);
            }
        }
    } else if (b == 128) {
        float acc = bm1[tid];
        for (int k = 0; k < HD; ++k) acc = fmaf(z[k], Wm1[(256 + k) * 256 + tid], acc);
        czw[tid] = acc;
    } else if (b >= 129 && b < 161) {
        const int i4 = (b - 129) * 256 + tid;   // float4 index into Hs0
        float4 v = make_float4(0.f, 0.f, 0.f, 0.f);
        if (i4 < 32) v = ((const float4*)z)[i4];  // row 0 = h0 = z
        ((float4*)(ws + HS0_OFF))[i4] = v;
    } else if (b == 161) {
        const uint4 zz = make_uint4(0, 0, 0, 0);
        ((uint4*)ancw)[tid] = zz;
        ((uint4*)ancw)[256 + tid] = zz;
        if (tid == 0) *lp_out = 0.0f;
    }

    gridbar(bar);

    // ---- sequential decode: t=1..255 real steps, t=256 = final GNN pass + MLP(255) ----
    for (int t = 1; t <= 256; ++t) {
        const int s = t - 1;
        const float* hsP = ws + ((s & 1) ? HS1_OFF : HS0_OFF);
        float* hsN = ws + ((t & 1) ? HS1_OFF : HS0_OFF);
        const int rmax  = (t <= 255) ? t : 255;
        const int tgate = (t <= 255) ? t : 257;   // 257: all rows take edges (final pass)
        const int tnew  = (t <= 255) ? t : -1;

        // P1: layer1(t) [G1]  ||  ct(t-1) [G4]
        if (b < 64)
            layer_rows(hsP, h1w, b1, z, pos_emb, tgtm, lds, b, rmax, tgate, tnew);
        else if (b == 192 && t >= 2)
            ct_calc(hsP, pos_emb, Wm1, czw, ctw, lds, s);
        gridbar(bar);

        // P2: layer2(t) [G2]  ||  MLP(t-1) [G3]
        if (b >= 64 && b < 128)
            layer_rows(h1w, hsN, b2, z, pos_emb, tgtm, lds, b - 64, rmax, tgate, -1);
        else if (b >= 128 && b < 192 && t >= 2)
            mlp_step(hsP, ctw, bm2, ancw, tgtm, lp_out, lds, b - 128, s);
        gridbar(bar);
    }

    // ---- X_out = Hs_final @ Wf + bf ; Hs_final in buffer 0 (t=256 is even) ----
    if (b < 64) {
        const int r = b * 4 + wv;
        const int f = lane & 15, kp = lane >> 4;
        const float* hrow = ws + HS0_OFF + r * HD + kp * 32;
        const float* wf = Wf + (kp * 32) * 16 + f;
        float sacc = 0.f;
#pragma unroll
        for (int k = 0; k < 32; ++k) sacc = fmaf(hrow[k], wf[k * 16], sacc);
        sacc += __shfl_xor(sacc, 16);
        sacc += __shfl_xor(sacc, 32);
        if (lane < 16) out[NN * NN + r * 16 + f] = sacc + bf[f];
    }
}

extern "C" void kernel_launch(void* const* d_in, const int* in_sizes, int n_in,
                              void* d_out, int out_size, void* d_ws, size_t ws_size,
                              hipStream_t stream)
{
    const float* z       = (const float*)d_in[0];
    const int*   targets = (const int*)d_in[1];
    const float* pos_emb = (const float*)d_in[2];
    const float* Ws1     = (const float*)d_in[3];
    const float* Wn1     = (const float*)d_in[4];
    const float* b1      = (const float*)d_in[5];
    const float* Ws2     = (const float*)d_in[6];
    const float* Wn2     = (const float*)d_in[7];
    const float* b2      = (const float*)d_in[8];
    const float* Wm1     = (const float*)d_in[9];
    const float* bm1     = (const float*)d_in[10];
    const float* Wm2     = (const float*)d_in[11];
    const float* bm2     = (const float*)d_in[12];
    const float* Wf      = (const float*)d_in[13];
    const float* bf      = (const float*)d_in[14];
    float* out = (float*)d_out;
    float* ws  = (float*)d_ws;

    // zero the barrier words (ws is poisoned 0xAA once; must be 0 each call)
    hipMemsetAsync(ws + BAR_OFF, 0, 16, stream);

    void* args[17] = {
        (void*)&z, (void*)&targets, (void*)&pos_emb,
        (void*)&Ws1, (void*)&Wn1, (void*)&b1,
        (void*)&Ws2, (void*)&Wn2, (void*)&b2,
        (void*)&Wm1, (void*)&bm1, (void*)&Wm2, (void*)&bm2,
        (void*)&Wf, (void*)&bf, (void*)&out, (void*)&ws
    };
    hipLaunchCooperativeKernel((const void*)fused_gnn, dim3(NBLK), dim3(256),
                               args, 0, stream);
}

// Round 3
// 9202.124 us; speedup vs baseline: 2.2336x; 1.1325x over previous
//
#include <hip/hip_runtime.h>

#define NN 256
#define HD 128
#define NBLK 96
#define GNN_NB 64

// ws float offsets
#define HS0_OFF   0
#define HS1_OFF   32768
#define H1_OFF    65536
#define CZ_OFF    98304
#define CT_OFF    98560
#define ANC_OFF   98816   // 2048 u32: ancT[i] word w bit b == anc[32w+b][i]
#define TGTM_OFF  100864  // 2048 u32: bitmask of tril(targets,-1) rows
#define FLAG_OFF  102912  // 96 flags, stride 32 u32 (128B lines)

// LDS float offsets
// GNN blocks: WW1 [0,16384): (Ws1,Wn1) interleaved float2 at [k*64+c]; WW2 [16384,32768)
//             ST 32768..33792: per-wave (h,m) float2 pairs (256 floats/wave)
// MLP blocks: WM [0,32768): Wm1_mid [k*256+c]; W2 32768..33024; HR 33024..33536; GT/LP after
#define ST_LDS 32768
#define W2_LDS 32768
#define HR_LDS 33024
#define GT_LDS 33536
#define LP_LDS 33544
#define LDS_FLOATS 33792

__device__ __forceinline__ void gridbar(unsigned* flags, unsigned ph) {
    __syncthreads();  // drains each wave's vmem (compiler emits vmcnt(0) before s_barrier)
    if (threadIdx.x == 0) {
        __builtin_amdgcn_fence(__ATOMIC_RELEASE, "agent");  // wbl2: push block's writes to IF
        __hip_atomic_store(flags + blockIdx.x * 32, ph, __ATOMIC_RELAXED, __HIP_MEMORY_SCOPE_AGENT);
    }
    if (threadIdx.x < NBLK) {
        while (__hip_atomic_load(flags + threadIdx.x * 32, __ATOMIC_RELAXED,
                                 __HIP_MEMORY_SCOPE_AGENT) < ph)
            __builtin_amdgcn_s_sleep(1);
    }
    __syncthreads();
    __builtin_amdgcn_fence(__ATOMIC_ACQUIRE, "agent");  // inv: drop stale L1/L2 lines
}

// One GNN layer, col-split: this block computes cols [ch*64, ch*64+64) for rows
// {rg*8+wv, rg*8+4+wv}. dst[r] = relu(src_r @ Ws + m_r @ Wn + b).
__device__ __forceinline__ void layer_rows(const float* __restrict__ src, float* __restrict__ dst,
    const float* __restrict__ bias, const float* __restrict__ z, const float* __restrict__ pos_emb,
    const unsigned* __restrict__ tgtm, const float* lds, int lofs, int ch, int rg,
    int rmax, int tgate, int tnew)
{
    const int tid = threadIdx.x, lane = tid & 63, wv = tid >> 6;
    const float2* WW = (const float2*)(lds + lofs);
    float2* ST = (float2*)(lds + ST_LDS) + wv * 128;
    const float2* s2 = (const float2*)src;

#pragma unroll
    for (int rr = 0; rr < 2; ++rr) {
        const int r = rg * 8 + rr * 4 + wv;
        if (r > rmax) continue;
        // gather m over parents j < r (only if row gated active: r < tgate)
        float2 m = make_float2(0.f, 0.f);
        const int jm = (r < tgate) ? r : 0;
        const unsigned* tg = tgtm + r * 8;
        const int nw = (jm + 31) >> 5;
        for (int w = 0; w < nw; ++w) {
            unsigned mask = tg[w];
            const int rem = jm - w * 32;
            if (rem < 32) mask &= (rem <= 0) ? 0u : ((1u << rem) - 1u);
            if (mask) {
                const float2* p = s2 + w * 2048 + lane;
#pragma unroll
                for (int bb = 0; bb < 32; ++bb) {
                    float2 v = p[bb * 64];
                    float sel = (float)((mask >> bb) & 1u);
                    m.x = fmaf(sel, v.x, m.x);
                    m.y = fmaf(sel, v.y, m.y);
                }
            }
        }
        float2 h;
        if (r == tnew) {
            h.x = z[2 * lane]     + pos_emb[r * HD + 2 * lane];
            h.y = z[2 * lane + 1] + pos_emb[r * HD + 2 * lane + 1];
        } else {
            h = s2[r * 64 + lane];
        }
        ST[2 * lane]     = make_float2(h.x, m.x);
        ST[2 * lane + 1] = make_float2(h.y, m.y);
        __threadfence_block();

        float acc = bias[ch * 64 + lane];
        const float2* Wp = WW + lane;
#pragma unroll 8
        for (int k = 0; k < HD; ++k) {
            const float2 w = Wp[k * 64];   // (Ws[k][c], Wn[k][c])
            const float2 s = ST[k];        // (h[k], m[k]) broadcast
            acc = fmaf(s.x, w.x, fmaf(s.y, w.y, acc));
        }
        dst[r * HD + ch * 64 + lane] = fmaxf(acc, 0.f);
        __threadfence_block();  // ST reuse safety for next rr
    }
}

// MLP blocks in P1: ct[c] = cz[c] + h_s@Wm1[0:128][c] + pos[s]@Wm1[384:512][c]; 8 cols/block
__device__ __forceinline__ void ct_calc(const float* __restrict__ hsP, const float* __restrict__ pos_emb,
    const float* __restrict__ Wm1, const float* __restrict__ cz, float* __restrict__ ct,
    float* lds, int mb, int s)
{
    const int tid = threadIdx.x;
    float* hp = lds + HR_LDS;  // [0:128) h_s, [128:256) pos[s]
    if (tid < 128)      hp[tid] = hsP[s * HD + tid];
    else if (tid < 256) hp[tid] = pos_emb[s * HD + (tid - 128)];
    __syncthreads();
    const int c = mb * 8 + (tid >> 5);
    const int sub = tid & 31;
    float acc = 0.f;
#pragma unroll
    for (int q = 0; q < 8; ++q) {
        const int kk = sub * 8 + q;  // 0..255
        const float w = (kk < 128) ? Wm1[kk * 256 + c] : Wm1[(256 + kk) * 256 + c];
        acc = fmaf(hp[kk], w, acc);
    }
#pragma unroll
    for (int off = 16; off; off >>= 1) acc += __shfl_xor(acc, off);
    if (sub == 0) ct[c] = acc + cz[c];
    __syncthreads();
}

// MLP blocks in P2: candidates i in {mb*4+wv, +128}, i < s. Wm1_mid in LDS.
__device__ __forceinline__ void mlp_step(const float* __restrict__ hsS, const float* __restrict__ ct,
    const float* __restrict__ bm2, unsigned* __restrict__ ancT, const unsigned* __restrict__ tgtm,
    float* __restrict__ lp_out, float* lds, int mb, int s)
{
    const int tid = threadIdx.x, lane = tid & 63, wv = tid >> 6;
    unsigned* gtl = (unsigned*)(lds + GT_LDS);
    if (tid < 8) gtl[tid] = tgtm[s * 8 + tid];
    if (tid == 0) lds[LP_LDS] = 0.0f;
    __syncthreads();
    float* hr = lds + HR_LDS + wv * 128;
    const float2* s2 = (const float2*)hsS;
#pragma unroll
    for (int rr = 0; rr < 2; ++rr) {
        const int i = mb * 4 + wv + rr * 128;
        if (i < s) {
            const float2 hv = s2[i * 64 + lane];
            hr[2 * lane] = hv.x; hr[2 * lane + 1] = hv.y;
            __threadfence_block();
            float4 a = make_float4(0.f, 0.f, 0.f, 0.f);
#pragma unroll 4
            for (int k = 0; k < HD; ++k) {
                const float hk = hr[k];
                const float4 w = *(const float4*)(lds + k * 256 + 4 * lane);
                a.x = fmaf(hk, w.x, a.x); a.y = fmaf(hk, w.y, a.y);
                a.z = fmaf(hk, w.z, a.z); a.w = fmaf(hk, w.w, a.w);
            }
            const float4 cc = *(const float4*)(ct + 4 * lane);
            const float4 w2 = *(const float4*)(lds + W2_LDS + 4 * lane);
            float sd = fmaxf(a.x + cc.x, 0.f) * w2.x
                     + fmaxf(a.y + cc.y, 0.f) * w2.y
                     + fmaxf(a.z + cc.z, 0.f) * w2.z
                     + fmaxf(a.w + cc.w, 0.f) * w2.w;
#pragma unroll
            for (int off = 32; off > 0; off >>= 1) sd += __shfl_xor(sd, off);
            if (lane == 0) {
                const float logit = sd + bm2[0];
                const float prob = 1.0f / (1.0f + expf(-logit));
                const uint4* ap = (const uint4*)(ancT + i * 8);
                const uint4 a0 = ap[0], a1 = ap[1];
                const unsigned cnt = __popc(a0.x) + __popc(a0.y) + __popc(a0.z) + __popc(a0.w)
                                   + __popc(a1.x) + __popc(a1.y) + __popc(a1.z) + __popc(a1.w);
                const unsigned has = (a0.x & gtl[0]) | (a0.y & gtl[1]) | (a0.z & gtl[2]) | (a0.w & gtl[3])
                                   | (a1.x & gtl[4]) | (a1.y & gtl[5]) | (a1.z & gtl[6]) | (a1.w & gtl[7]);
                const float supp = ldexpf(1.0f, -(int)cnt);  // 0.5^cnt exact
                const float adj = prob * supp;
                const unsigned gt = (gtl[i >> 5] >> (i & 31)) & 1u;
                const float lpv = gt ? logf(adj + 1e-12f) : logf(1.0f - adj + 1e-12f);
                atomicAdd((float*)(lds + LP_LDS), lpv);
                if (has | gt) ancT[i * 8 + (s >> 5)] |= (1u << (s & 31));  // anc[s][i]
            }
        }
    }
    __syncthreads();
    if (tid == 0) {
        const float v = lds[LP_LDS];
        if (v != 0.0f) atomicAdd(lp_out, v);
    }
}

extern "C" __global__ void __launch_bounds__(256)
fused_gnn(const float* z, const int* targets, const float* pos_emb,
          const float* Ws1, const float* Wn1, const float* b1,
          const float* Ws2, const float* Wn2, const float* b2,
          const float* Wm1, const float* bm1, const float* Wm2, const float* bm2,
          const float* Wf, const float* bf, float* out, float* ws)
{
    __shared__ __align__(16) float lds[LDS_FLOATS];
    const int b = blockIdx.x;
    const int tid = threadIdx.x, lane = tid & 63, wv = tid >> 6;

    float* h1w = ws + H1_OFF;
    float* czw = ws + CZ_OFF;
    float* ctw = ws + CT_OFF;
    unsigned* ancw = (unsigned*)(ws + ANC_OFF);
    unsigned* tgtm = (unsigned*)(ws + TGTM_OFF);
    unsigned* flags = (unsigned*)(ws + FLAG_OFF);
    float* lp_out = out + NN * NN + NN * 16;

    const int ch = b & 1, rg = b >> 1;  // GNN blocks: col-half, row-group

    // ---- init: LDS weight staging + global state ----
    if (b < GNN_NB) {
        for (int idx = tid; idx < 8192; idx += 256) {
            const int k = idx >> 6, c = idx & 63;
            lds[idx * 2]             = Ws1[k * HD + ch * 64 + c];
            lds[idx * 2 + 1]         = Wn1[k * HD + ch * 64 + c];
            lds[16384 + idx * 2]     = Ws2[k * HD + ch * 64 + c];
            lds[16384 + idx * 2 + 1] = Wn2[k * HD + ch * 64 + c];
        }
        // tgt output + bitmasks, rows r = b*4+wv
        const int r = b * 4 + wv;
        const int4 tv = ((const int4*)(targets + r * NN))[lane];
        float4 ov;
        ov.x = (4 * lane     < r) ? (float)tv.x : 0.f;
        ov.y = (4 * lane + 1 < r) ? (float)tv.y : 0.f;
        ov.z = (4 * lane + 2 < r) ? (float)tv.z : 0.f;
        ov.w = (4 * lane + 3 < r) ? (float)tv.w : 0.f;
        ((float4*)(out + r * NN))[lane] = ov;
#pragma unroll
        for (int q = 0; q < 4; ++q) {
            const int j = q * 64 + lane;
            const unsigned long long bbm = __ballot(j < r && targets[r * NN + j] != 0);
            if (lane == 0) {
                tgtm[r * 8 + 2 * q]     = (unsigned)bbm;
                tgtm[r * 8 + 2 * q + 1] = (unsigned)(bbm >> 32);
            }
        }
    } else {
        for (int idx = tid; idx < 32768; idx += 256)
            lds[idx] = Wm1[32768 + idx];           // Wm1_mid rows 128..255
        if (tid < 256) lds[W2_LDS + tid] = Wm2[tid];
        // Hs0 init: 32 blocks x 256 float4 = exactly 32768 floats
        const int i4 = (b - GNN_NB) * 256 + tid;
        float4 v = make_float4(0.f, 0.f, 0.f, 0.f);
        if (i4 < 32) v = ((const float4*)z)[i4];   // row 0 = h0 = z
        ((float4*)(ws + HS0_OFF))[i4] = v;
        if (b == GNN_NB) {
            float acc = bm1[tid];
            for (int k = 0; k < HD; ++k) acc = fmaf(z[k], Wm1[(256 + k) * 256 + tid], acc);
            czw[tid] = acc;
            const uint4 zz = make_uint4(0, 0, 0, 0);
            ((uint4*)ancw)[tid] = zz;
            ((uint4*)ancw)[256 + tid] = zz;
            if (tid == 0) *lp_out = 0.0f;
        }
    }

    unsigned ph = 1;
    gridbar(flags, ph++);

    // ---- sequential decode: t=1..255, t=256 = final full-graph pass + MLP(255) ----
    for (int t = 1; t <= 256; ++t) {
        const int s = t - 1;
        const float* hsP = ws + ((s & 1) ? HS1_OFF : HS0_OFF);
        float* hsN = ws + ((t & 1) ? HS1_OFF : HS0_OFF);
        const int rmax  = (t <= 255) ? t : 255;
        const int tgate = (t <= 255) ? t : 300;
        const int tnew  = (t <= 255) ? t : -1;

        // P1: layer1(t) [GNN]  ||  ct(t-1) [MLP blocks]
        if (b < GNN_NB)
            layer_rows(hsP, h1w, b1, z, pos_emb, tgtm, lds, 0, ch, rg, rmax, tgate, tnew);
        else if (t >= 2)
            ct_calc(hsP, pos_emb, Wm1, czw, ctw, lds, b - GNN_NB, s);
        gridbar(flags, ph++);

        // P2: layer2(t) [GNN]  ||  MLP(t-1) [MLP blocks]
        if (b < GNN_NB)
            layer_rows(h1w, hsN, b2, z, pos_emb, tgtm, lds, 16384, ch, rg, rmax, tgate, -1);
        else if (t >= 2)
            mlp_step(hsP, ctw, bm2, ancw, tgtm, lp_out, lds, b - GNN_NB, s);
        gridbar(flags, ph++);
    }

    // ---- X_out = Hs_final @ Wf + bf (Hs final in buf 0; t=256 even) ----
    if (b < GNN_NB) {
        const int r = b * 4 + wv;
        const int f = lane & 15, kp = lane >> 4;
        const float* hrow = ws + HS0_OFF + r * HD + kp * 32;
        const float* wf = Wf + (kp * 32) * 16 + f;
        float sacc = 0.f;
#pragma unroll
        for (int k = 0; k < 32; ++k) sacc = fmaf(hrow[k], wf[k * 16], sacc);
        sacc += __shfl_xor(sacc, 16);
        sacc += __shfl_xor(sacc, 32);
        if (lane < 16) out[NN * NN + r * 16 + f] = sacc + bf[f];
    }
}

extern "C" void kernel_launch(void* const* d_in, const int* in_sizes, int n_in,
                              void* d_out, int out_size, void* d_ws, size_t ws_size,
                              hipStream_t stream)
{
    const float* z       = (const float*)d_in[0];
    const int*   targets = (const int*)d_in[1];
    const float* pos_emb = (const float*)d_in[2];
    const float* Ws1     = (const float*)d_in[3];
    const float* Wn1     = (const float*)d_in[4];
    const float* b1      = (const float*)d_in[5];
    const float* Ws2     = (const float*)d_in[6];
    const float* Wn2     = (const float*)d_in[7];
    const float* b2      = (const float*)d_in[8];
    const float* Wm1     = (const float*)d_in[9];
    const float* bm1     = (const float*)d_in[10];
    const float* Wm2     = (const float*)d_in[11];
    const float* bm2     = (const float*)d_in[12];
    const float* Wf      = (const float*)d_in[13];
    const float* bf      = (const float*)d_in[14];
    float* out = (float*)d_out;
    float* ws  = (float*)d_ws;

    // zero the flag lines (generation counters start fresh each call)
    hipMemsetAsync(ws + FLAG_OFF, 0, NBLK * 32 * sizeof(unsigned), stream);

    void* args[17] = {
        (void*)&z, (void*)&targets, (void*)&pos_emb,
        (void*)&Ws1, (void*)&Wn1, (void*)&b1,
        (void*)&Ws2, (void*)&Wn2, (void*)&b2,
        (void*)&Wm1, (void*)&bm1, (void*)&Wm2, (void*)&bm2,
        (void*)&Wf, (void*)&bf, (void*)&out, (void*)&ws
    };
    hipLaunchCooperativeKernel((const void*)fused_gnn, dim3(NBLK), dim3(256),
                               args, 0, stream);
}

// Round 5
// 6390.412 us; speedup vs baseline: 3.2164x; 1.4400x over previous
//
#include <hip/hip_runtime.h>

#define NN 256
#define HD 128
#define GNN_NB 64
#define MLP_NB 32
#define NBLK (GNN_NB + MLP_NB)

// ws float offsets (all cross-block-mutable data accessed ONLY via sc1 atomics)
#define HS0_OFF 0
#define HS1_OFF 32768
#define H1_OFF  65536
#define FLAG_OFF 98304   // 96 flags, stride 32 u32 (128B apart)

// LDS float offsets
// GNN blocks: W [0,32768) (Ws,Wn) float2-interleaved; CH [32768,36864) 32-row chunk;
//             ST [36864,38912) per-wave staging; MK [38912,38928) 64 u32 row masks
// MLP blocks: WM [0,32768) Wm1_mid; W2 [32768,33024); CT [33024,33280); CZ [33280,33536);
//             HP [33536,33792); HR [33792,34304); ANC@34304 (64 u32); LP@34368;
//             TGTM [34432,36480) full 256x8 u32 mask table
#define CH_LDS   32768
#define ST_LDS   36864
#define MK_LDS   38912
#define W2_LDS   32768
#define CT_LDS   33024
#define CZ_LDS   33280
#define HP_LDS   33536
#define HR_LDS   33792
#define ANC_LDS  34304
#define LP_LDS   34368
#define TGTM_LDS 34432
#define LDS_FLOATS 38976

// ---- device-coherent access (relaxed agent atomics -> sc1, bypass L1/L2) ----
__device__ __forceinline__ float2 ldc_f2(const float* p) {
    unsigned long long u = __hip_atomic_load((const unsigned long long*)p,
                                             __ATOMIC_RELAXED, __HIP_MEMORY_SCOPE_AGENT);
    float2 r;
    r.x = __uint_as_float((unsigned)u);
    r.y = __uint_as_float((unsigned)(u >> 32));
    return r;
}
__device__ __forceinline__ void stc_f(float* p, float v) {
    __hip_atomic_store((unsigned*)p, __float_as_uint(v),
                       __ATOMIC_RELAXED, __HIP_MEMORY_SCOPE_AGENT);
}
__device__ __forceinline__ void stc_f2(float* p, float2 v) {
    unsigned long long u = ((unsigned long long)__float_as_uint(v.y) << 32)
                         | __float_as_uint(v.x);
    __hip_atomic_store((unsigned long long*)p, u,
                       __ATOMIC_RELAXED, __HIP_MEMORY_SCOPE_AGENT);
}

__device__ __forceinline__ void gridbar(unsigned* flags, unsigned ph) {
    __syncthreads();  // compiler emits vmcnt(0) before s_barrier -> all sc1 stores retired at IF
    if (threadIdx.x == 0)
        __hip_atomic_store(flags + blockIdx.x * 32, ph,
                           __ATOMIC_RELAXED, __HIP_MEMORY_SCOPE_AGENT);
    if (threadIdx.x < NBLK) {
        while (__hip_atomic_load(flags + threadIdx.x * 32,
                                 __ATOMIC_RELAXED, __HIP_MEMORY_SCOPE_AGENT) < ph)
            __builtin_amdgcn_s_sleep(1);
    }
    __syncthreads();
    asm volatile("" ::: "memory");  // compiler reorder fence only; data path is sc1
}

// One GNN layer, col-split: block computes cols [ch*64,ch*64+64) of rows {rg*8+wv, rg*8+4+wv}
__device__ __forceinline__ void layer_rows(const float* src, float* dst, const float* bias,
    const float* z, const float* pos_emb, float* lds,
    int lofs, int ch, int rg, int rmax, int tgate, int tnew)
{
    const int tid = threadIdx.x, lane = tid & 63, wv = tid >> 6;
    const int r0 = rg * 8 + wv, r1 = r0 + 4;
    const unsigned* mk = (const unsigned*)(lds + MK_LDS);
    const unsigned* tg0 = mk + (wv * 2) * 8;
    const unsigned* tg1 = mk + (wv * 2 + 1) * 8;
    const int nchunk = (rmax + 32) >> 5;
    const bool act0 = (r0 < tgate), act1 = (r1 < tgate);

    float2 m0 = make_float2(0.f, 0.f), m1 = m0, h0 = m0, h1v = m0;
    float2 p0, p1, p2, p3, p4, p5, p6, p7;
    {   // prologue: stage chunk 0 (rows 0..31)
        const float* p = src + 2 * tid;
        p0 = ldc_f2(p);        p1 = ldc_f2(p + 512);
        p2 = ldc_f2(p + 1024); p3 = ldc_f2(p + 1536);
        p4 = ldc_f2(p + 2048); p5 = ldc_f2(p + 2560);
        p6 = ldc_f2(p + 3072); p7 = ldc_f2(p + 3584);
        float2* cb2 = (float2*)(lds + CH_LDS);
        cb2[tid] = p0;        cb2[tid + 256] = p1;
        cb2[tid + 512] = p2;  cb2[tid + 768] = p3;
        cb2[tid + 1024] = p4; cb2[tid + 1280] = p5;
        cb2[tid + 1536] = p6; cb2[tid + 1792] = p7;
    }
    __syncthreads();
    const float* cb = lds + CH_LDS;

    for (int c = 0; c < nchunk; ++c) {
        const bool more = (c + 1 < nchunk);
        if (more) {  // issue next-chunk loads; latency hides under accumulate
            const float* p = src + (c + 1) * 4096 + 2 * tid;
            p0 = ldc_f2(p);        p1 = ldc_f2(p + 512);
            p2 = ldc_f2(p + 1024); p3 = ldc_f2(p + 1536);
            p4 = ldc_f2(p + 2048); p5 = ldc_f2(p + 2560);
            p6 = ldc_f2(p + 3072); p7 = ldc_f2(p + 3584);
        }
        // masked accumulate over set bits (wave-uniform scalar-driven loop)
        unsigned w0m = act0 ? (unsigned)__builtin_amdgcn_readfirstlane((int)tg0[c]) : 0u;
        while (w0m) {
            const int bb = __ffs(w0m) - 1; w0m &= w0m - 1u;
            const float2 v = *(const float2*)(cb + bb * HD + 2 * lane);
            m0.x += v.x; m0.y += v.y;
        }
        unsigned w1m = act1 ? (unsigned)__builtin_amdgcn_readfirstlane((int)tg1[c]) : 0u;
        while (w1m) {
            const int bb = __ffs(w1m) - 1; w1m &= w1m - 1u;
            const float2 v = *(const float2*)(cb + bb * HD + 2 * lane);
            m1.x += v.x; m1.y += v.y;
        }
        if ((r0 >> 5) == c) h0  = *(const float2*)(cb + (r0 & 31) * HD + 2 * lane);
        if ((r1 >> 5) == c) h1v = *(const float2*)(cb + (r1 & 31) * HD + 2 * lane);
        __syncthreads();  // all waves done reading chunk c
        if (more) {
            float2* cb2 = (float2*)(lds + CH_LDS);
            cb2[tid] = p0;        cb2[tid + 256] = p1;
            cb2[tid + 512] = p2;  cb2[tid + 768] = p3;
            cb2[tid + 1024] = p4; cb2[tid + 1280] = p5;
            cb2[tid + 1536] = p6; cb2[tid + 1792] = p7;
            __syncthreads();  // chunk c+1 visible
        }
    }
    if (r0 == tnew) {
        h0.x = z[2 * lane]     + pos_emb[r0 * HD + 2 * lane];
        h0.y = z[2 * lane + 1] + pos_emb[r0 * HD + 2 * lane + 1];
    }
    if (r1 == tnew) {
        h1v.x = z[2 * lane]     + pos_emb[r1 * HD + 2 * lane];
        h1v.y = z[2 * lane + 1] + pos_emb[r1 * HD + 2 * lane + 1];
    }

    // per-wave (h,m) staging; wave-local LDS region
    float* st = lds + ST_LDS + wv * 512;
    st[4 * lane]     = h0.x; st[4 * lane + 1] = m0.x;
    st[4 * lane + 2] = h0.y; st[4 * lane + 3] = m0.y;
    st[256 + 4 * lane]     = h1v.x; st[256 + 4 * lane + 1] = m1.x;
    st[256 + 4 * lane + 2] = h1v.y; st[256 + 4 * lane + 3] = m1.y;
    __threadfence_block();

    const float bb_ = bias[ch * 64 + lane];
    float acc0 = bb_, acc1 = bb_;
    const float2* Wp = (const float2*)(lds + lofs) + lane;
    const float2* S0 = (const float2*)st;
    const float2* S1 = (const float2*)(st + 256);
#pragma unroll 8
    for (int k = 0; k < HD; ++k) {
        const float2 w = Wp[k * 64];      // (Ws[k][c], Wn[k][c])
        const float2 a = S0[k], b2 = S1[k];
        acc0 = fmaf(a.x,  w.x, fmaf(a.y,  w.y, acc0));
        acc1 = fmaf(b2.x, w.x, fmaf(b2.y, w.y, acc1));
    }
    if (r0 <= rmax) stc_f(dst + r0 * HD + ch * 64 + lane, fmaxf(acc0, 0.f));
    if (r1 <= rmax) stc_f(dst + r1 * HD + ch * 64 + lane, fmaxf(acc1, 0.f));
}

// MLP blocks, P1: ct[c] = cz[c] + h_s@Wm1[0:128] + pos_s@Wm1[384:512]  (block-local)
__device__ __forceinline__ void ct_calc(const float* hsP, const float* pos_emb,
                                        const float* Wm1, float* lds, int s)
{
    const int tid = threadIdx.x;
    float* hp = lds + HP_LDS;
    if (tid < 64) {
        const float2 v = ldc_f2(hsP + s * HD + 2 * tid);
        hp[2 * tid] = v.x; hp[2 * tid + 1] = v.y;
    } else if (tid < 128) {
        const int l2 = tid - 64;
        hp[128 + 2 * l2]     = pos_emb[s * HD + 2 * l2];
        hp[128 + 2 * l2 + 1] = pos_emb[s * HD + 2 * l2 + 1];
    }
    __syncthreads();
    float acc = lds[CZ_LDS + tid];
    const float* w0 = Wm1 + tid;              // rows 0..127   (h_t block)
    const float* w1 = Wm1 + 384 * 256 + tid;  // rows 384..511 (pos block)
#pragma unroll 4
    for (int k = 0; k < HD; ++k) {
        acc = fmaf(hp[k],       w0[k * 256], acc);
        acc = fmaf(hp[128 + k], w1[k * 256], acc);
    }
    lds[CT_LDS + tid] = acc;
}

__device__ __forceinline__ void mlp_one(const float2 hv, int slot, int i, int s,
                                        const float* bm2, float* lds,
                                        const unsigned* gtl, int lane, int wv)
{
    unsigned* ancl = (unsigned*)(lds + ANC_LDS);
    float* hr = lds + HR_LDS + wv * 128;
    hr[2 * lane] = hv.x; hr[2 * lane + 1] = hv.y;
    __threadfence_block();
    float4 a = make_float4(0.f, 0.f, 0.f, 0.f);
    const float4* W4 = (const float4*)lds + lane;  // Wm1_mid[k*256 + 4*lane]
#pragma unroll 4
    for (int k = 0; k < HD; ++k) {
        const float hk = hr[k];
        const float4 w = W4[k * 64];
        a.x = fmaf(hk, w.x, a.x); a.y = fmaf(hk, w.y, a.y);
        a.z = fmaf(hk, w.z, a.z); a.w = fmaf(hk, w.w, a.w);
    }
    const float4 cc = *(const float4*)(lds + CT_LDS + 4 * lane);
    const float4 w2 = *(const float4*)(lds + W2_LDS + 4 * lane);
    float sd = fmaxf(a.x + cc.x, 0.f) * w2.x + fmaxf(a.y + cc.y, 0.f) * w2.y
             + fmaxf(a.z + cc.z, 0.f) * w2.z + fmaxf(a.w + cc.w, 0.f) * w2.w;
#pragma unroll
    for (int off = 32; off > 0; off >>= 1) sd += __shfl_xor(sd, off);
    if (lane == 0) {
        const float logit = sd + bm2[0];
        const float prob = 1.f / (1.f + expf(-logit));
        unsigned cnt = 0, has = 0;
#pragma unroll
        for (int w = 0; w < 8; ++w) {
            const unsigned av = ancl[slot * 8 + w];
            cnt += __popc(av);
            has |= av & gtl[w];
        }
        const float supp = ldexpf(1.f, -(int)cnt);  // 0.5^cnt exact incl. underflow
        const float adj = prob * supp;
        const unsigned gt = (gtl[i >> 5] >> (i & 31)) & 1u;
        const float lpv = gt ? logf(adj + 1e-12f) : logf(1.f - adj + 1e-12f);
        atomicAdd((float*)(lds + LP_LDS), lpv);
        if (has | gt) ancl[slot * 8 + (s >> 5)] |= (1u << (s & 31));  // anc[s][i]
    }
}

__device__ __forceinline__ void mlp_step(const float* hsP, const float* bm2,
                                         float* lds, int mb, int s)
{
    const int lane = threadIdx.x & 63, wv = threadIdx.x >> 6;
    const unsigned* gtl = (const unsigned*)(lds + TGTM_LDS) + s * 8;
    const int i0 = mb * 8 + wv, i1 = i0 + 4;
    float2 hva = make_float2(0.f, 0.f), hvb = hva;
    if (i0 < s) hva = ldc_f2(hsP + i0 * HD + 2 * lane);  // both loads in flight
    if (i1 < s) hvb = ldc_f2(hsP + i1 * HD + 2 * lane);
    if (i0 < s) mlp_one(hva, wv,     i0, s, bm2, lds, gtl, lane, wv);
    if (i1 < s) mlp_one(hvb, wv + 4, i1, s, bm2, lds, gtl, lane, wv);
}

extern "C" __global__ void __launch_bounds__(256)
fused_gnn(const float* z, const int* targets, const float* pos_emb,
          const float* Ws1, const float* Wn1, const float* b1,
          const float* Ws2, const float* Wn2, const float* b2,
          const float* Wm1, const float* bm1, const float* Wm2, const float* bm2,
          const float* Wf, const float* bf, float* out, float* ws)
{
    __shared__ __align__(16) float lds[LDS_FLOATS];
    const int b = blockIdx.x;
    const int tid = threadIdx.x, lane = tid & 63, wv = tid >> 6;

    float* h1w = ws + H1_OFF;
    unsigned* flags = (unsigned*)(ws + FLAG_OFF);
    float* lp_out = out + NN * NN + NN * 16;

    const int ch = b & 1, rg = b >> 1;   // GNN blocks
    const int mb = b - GNN_NB;           // MLP blocks

    // ---- init ----
    if (b < GNN_NB) {
        for (int idx = tid; idx < 8192; idx += 256) {
            const int k = idx >> 6, c = idx & 63;
            lds[2 * idx]             = Ws1[k * HD + ch * 64 + c];
            lds[2 * idx + 1]         = Wn1[k * HD + ch * 64 + c];
            lds[16384 + 2 * idx]     = Ws2[k * HD + ch * 64 + c];
            lds[16384 + 2 * idx + 1] = Wn2[k * HD + ch * 64 + c];
        }
        // output 0: tgt rows r = b*4+wv (plain cached stores; read only by host)
        {
            const int r = b * 4 + wv;
            const int4 tv = ((const int4*)(targets + r * NN))[lane];
            float4 ov;
            ov.x = (4 * lane     < r) ? (float)tv.x : 0.f;
            ov.y = (4 * lane + 1 < r) ? (float)tv.y : 0.f;
            ov.z = (4 * lane + 2 < r) ? (float)tv.z : 0.f;
            ov.w = (4 * lane + 3 < r) ? (float)tv.w : 0.f;
            ((float4*)(out + r * NN))[lane] = ov;
        }
        // this block's own row masks (rows rg*8+rr*4+wv) -> MK_LDS
        unsigned* mk = (unsigned*)(lds + MK_LDS);
#pragma unroll
        for (int rr = 0; rr < 2; ++rr) {
            const int r = rg * 8 + rr * 4 + wv;
#pragma unroll
            for (int q = 0; q < 4; ++q) {
                const int j = q * 64 + lane;
                const unsigned long long bm = __ballot(j < r && targets[r * NN + j] != 0);
                if (lane == 0) {
                    mk[(wv * 2 + rr) * 8 + 2 * q]     = (unsigned)bm;
                    mk[(wv * 2 + rr) * 8 + 2 * q + 1] = (unsigned)(bm >> 32);
                }
            }
        }
    } else {
        for (int idx = tid; idx < 32768; idx += 256)
            lds[idx] = Wm1[32768 + idx];             // Wm1 rows 128..255 (Hs block)
        lds[W2_LDS + tid] = Wm2[tid];
        float acc = bm1[tid];
        for (int k = 0; k < HD; ++k) acc = fmaf(z[k], Wm1[(256 + k) * 256 + tid], acc);
        lds[CZ_LDS + tid] = acc;
        if (tid < 64) ((unsigned*)(lds + ANC_LDS))[tid] = 0u;
        if (tid == 0) lds[LP_LDS] = 0.f;
        // full mask table in LDS: wave wv builds rows wv*64..wv*64+63
        {
            unsigned* tg = (unsigned*)(lds + TGTM_LDS);
            for (int rr = 0; rr < 64; ++rr) {
                const int r = wv * 64 + rr;
#pragma unroll
                for (int q = 0; q < 4; ++q) {
                    const int j = q * 64 + lane;
                    const unsigned long long bm = __ballot(j < r && targets[r * NN + j] != 0);
                    if (lane == 0) {
                        tg[r * 8 + 2 * q]     = (unsigned)bm;
                        tg[r * 8 + 2 * q + 1] = (unsigned)(bm >> 32);
                    }
                }
            }
        }
        // Hs0 init (coherent stores): 32 blocks x 256 threads x 4 floats
        {
            const int i4 = mb * 256 + tid;
            float2 v0 = make_float2(0.f, 0.f), v1 = v0;
            if (i4 < 32) {  // row 0 = h0 = z
                v0 = make_float2(z[i4 * 4], z[i4 * 4 + 1]);
                v1 = make_float2(z[i4 * 4 + 2], z[i4 * 4 + 3]);
            }
            stc_f2(ws + HS0_OFF + i4 * 4, v0);
            stc_f2(ws + HS0_OFF + i4 * 4 + 2, v1);
        }
        if (mb == 0 && tid == 0)
            __hip_atomic_store((unsigned*)lp_out, 0u, __ATOMIC_RELAXED,
                               __HIP_MEMORY_SCOPE_AGENT);
    }

    unsigned ph = 1;
    gridbar(flags, ph); ph++;

    // ---- t=1..255 decode steps; t=256 = final full-graph pass (+ MLP(255)) ----
    for (int t = 1; t <= 256; ++t) {
        const int s = t - 1;
        const float* hsP = ws + ((s & 1) ? HS1_OFF : HS0_OFF);
        float* hsN = ws + ((t & 1) ? HS1_OFF : HS0_OFF);
        const int rmax  = (t <= 255) ? t : 255;
        const int tgate = (t <= 255) ? t : 300;
        const int tnew  = (t <= 255) ? t : -1;

        // P1: layer1(t) [GNN]  ||  ct(t-1) [MLP]
        if (b < GNN_NB)
            layer_rows(hsP, h1w, b1, z, pos_emb, lds, 0, ch, rg, rmax, tgate, tnew);
        else if (t >= 2)
            ct_calc(hsP, pos_emb, Wm1, lds, s);
        gridbar(flags, ph); ph++;

        // P2: layer2(t) [GNN]  ||  MLP(t-1) [MLP]
        if (b < GNN_NB)
            layer_rows(h1w, hsN, b2, z, pos_emb, lds, 16384, ch, rg, rmax, tgate, -1);
        else if (t >= 2)
            mlp_step(hsP, bm2, lds, mb, s);
        gridbar(flags, ph); ph++;
    }

    // ---- epilogue ----
    if (b < GNN_NB) {
        // X_out = Hs_final @ Wf + bf ; final Hs in buffer 0 (t=256 even)
        const int r = b * 4 + wv;
        float* strow = lds + CH_LDS + wv * 128;
        const float2 hv = ldc_f2(ws + HS0_OFF + r * HD + 2 * lane);
        strow[2 * lane] = hv.x; strow[2 * lane + 1] = hv.y;
        __threadfence_block();
        const int f = lane & 15, kp = lane >> 4;
        float sacc = 0.f;
#pragma unroll
        for (int k = 0; k < 32; ++k)
            sacc = fmaf(strow[kp * 32 + k], Wf[(kp * 32 + k) * 16 + f], sacc);
        sacc += __shfl_xor(sacc, 16);
        sacc += __shfl_xor(sacc, 32);
        if (lane < 16) out[NN * NN + r * 16 + f] = sacc + bf[f];
    } else {
        __syncthreads();
        if (tid == 0) atomicAdd(lp_out, lds[LP_LDS]);
    }
}

extern "C" void kernel_launch(void* const* d_in, const int* in_sizes, int n_in,
                              void* d_out, int out_size, void* d_ws, size_t ws_size,
                              hipStream_t stream)
{
    const float* z       = (const float*)d_in[0];
    const int*   targets = (const int*)d_in[1];
    const float* pos_emb = (const float*)d_in[2];
    const float* Ws1     = (const float*)d_in[3];
    const float* Wn1     = (const float*)d_in[4];
    const float* b1      = (const float*)d_in[5];
    const float* Ws2     = (const float*)d_in[6];
    const float* Wn2     = (const float*)d_in[7];
    const float* b2      = (const float*)d_in[8];
    const float* Wm1     = (const float*)d_in[9];
    const float* bm1     = (const float*)d_in[10];
    const float* Wm2     = (const float*)d_in[11];
    const float* bm2     = (const float*)d_in[12];
    const float* Wf      = (const float*)d_in[13];
    const float* bf      = (const float*)d_in[14];
    float* out = (float*)d_out;
    float* ws  = (float*)d_ws;

    // zero the flag lines (memset kernel's end-of-kernel writeback makes the
    // zeros visible to the cooperative kernel's sc1 loads)
    (void)hipMemsetAsync(ws + FLAG_OFF, 0, NBLK * 32 * sizeof(unsigned), stream);

    void* args[17] = {
        (void*)&z, (void*)&targets, (void*)&pos_emb,
        (void*)&Ws1, (void*)&Wn1, (void*)&b1,
        (void*)&Ws2, (void*)&Wn2, (void*)&b2,
        (void*)&Wm1, (void*)&bm1, (void*)&Wm2, (void*)&bm2,
        (void*)&Wf, (void*)&bf, (void*)&out, (void*)&ws
    };
    (void)hipLaunchCooperativeKernel((const void*)fused_gnn, dim3(NBLK), dim3(256),
                                     args, 0, stream);
}

// Round 6
// 5467.385 us; speedup vs baseline: 3.7594x; 1.1688x over previous
//
#include <hip/hip_runtime.h>

#define NN 256
#define HD 128
#define GNN_NB 32
#define MLP_NB 16
#define NBLK (GNN_NB + MLP_NB)
#define NTHR 512

// ws float offsets (cross-block-mutable data accessed ONLY via sc1 atomics)
#define HS0_OFF 0
#define HS1_OFF 32768
#define H1_OFF  65536
#define FLAG_OFF 98304   // 48 flags, stride 32 u32 (128B apart)

// LDS layout (floats), union across block roles:
// GNN: WW1 [0,16384) (Ws1,Wn1) interleaved; WW2 [16384,32768); CB/ST [32768,36864);
//      MK @36864 (128 u32: per-wave 2 rows x 8 mask words)
// MLP: WM [0,32768) Wm1 rows 128..255; W2 [32768,33024); CT [33024,33280);
//      CZ [33280,33536); HP [33536,33792); HR/PART [33792,34816);
//      TGTM [34816,36864) (2048 u32); ANC @36864 (128 u32); LP @36992
#define CB_LDS   32768
#define MK_LDS   36864
#define W2_LDS   32768
#define CT_LDS   33024
#define CZ_LDS   33280
#define HP_LDS   33536
#define HR_LDS   33792
#define TGTM_LDS 34816
#define ANC_LDS  36864
#define LP_LDS   36992
#define LDS_FLOATS 37056

// ---- device-coherent access (relaxed agent atomics -> sc1, bypass L1/L2) ----
__device__ __forceinline__ float2 ldc_f2(const float* p) {
    unsigned long long u = __hip_atomic_load((const unsigned long long*)p,
                                             __ATOMIC_RELAXED, __HIP_MEMORY_SCOPE_AGENT);
    float2 r;
    r.x = __uint_as_float((unsigned)u);
    r.y = __uint_as_float((unsigned)(u >> 32));
    return r;
}
__device__ __forceinline__ void stc_f(float* p, float v) {
    __hip_atomic_store((unsigned*)p, __float_as_uint(v),
                       __ATOMIC_RELAXED, __HIP_MEMORY_SCOPE_AGENT);
}
__device__ __forceinline__ void stc_f2(float* p, float2 v) {
    unsigned long long u = ((unsigned long long)__float_as_uint(v.y) << 32)
                         | __float_as_uint(v.x);
    __hip_atomic_store((unsigned long long*)p, u,
                       __ATOMIC_RELAXED, __HIP_MEMORY_SCOPE_AGENT);
}

__device__ __forceinline__ void gridbar(unsigned* flags, unsigned ph) {
    __syncthreads();  // compiler drains vmem before s_barrier -> sc1 stores at IF
    if (threadIdx.x == 0)
        __hip_atomic_store(flags + blockIdx.x * 32, ph,
                           __ATOMIC_RELAXED, __HIP_MEMORY_SCOPE_AGENT);
    if (threadIdx.x < NBLK) {
        while (__hip_atomic_load(flags + threadIdx.x * 32,
                                 __ATOMIC_RELAXED, __HIP_MEMORY_SCOPE_AGENT) < ph)
            __builtin_amdgcn_s_sleep(1);
    }
    __syncthreads();
    asm volatile("" ::: "memory");  // compiler reorder fence; data path is sc1
}

// One GNN layer. Block = cols [ch*64,ch*64+64) x rows [rg*16, rg*16+16).
// Wave wv owns rows r0=rg*16+wv, r1=r0+8. dst[r] = relu(src_r@Ws + m_r@Wn + b).
__device__ __forceinline__ void layer_rows(const float* src, float* dst, const float* bias,
    const float* z, const float* pos_emb, float* lds, int lofs, int ch, int rg,
    int rmax, int tgate, int tnew)
{
    if (rg * 16 > rmax) return;  // block-uniform idle
    const int tid = threadIdx.x, lane = tid & 63, wv = tid >> 6;
    const int r0 = rg * 16 + wv, r1 = r0 + 8;
    const int rmaxblk = min(rmax, rg * 16 + 15);
    const int nchunk = (rmaxblk >> 5) + 1;
    const unsigned* mk = (const unsigned*)(lds + MK_LDS);
    float* cb = lds + CB_LDS;

    float2 m0 = make_float2(0.f, 0.f), m1 = m0, h0 = m0, h1v = m0;
    float2 p0, p1, p2, p3;
    {   // stage chunk 0 (rows 0..31): 512 thr x 4 float2 = 16KB
        const float* p = src + 2 * tid;
        p0 = ldc_f2(p);        p1 = ldc_f2(p + 1024);
        p2 = ldc_f2(p + 2048); p3 = ldc_f2(p + 3072);
        float2* cb2 = (float2*)cb;
        cb2[tid] = p0; cb2[tid + 512] = p1; cb2[tid + 1024] = p2; cb2[tid + 1536] = p3;
    }
    __syncthreads();

    const bool act0 = (r0 < tgate) && (r0 <= rmaxblk);
    const bool act1 = (r1 < tgate) && (r1 <= rmaxblk);

    for (int c = 0; c < nchunk; ++c) {
        const bool more = (c + 1 < nchunk);
        if (more) {  // prefetch next chunk; latency hides under accumulate
            const float* p = src + (c + 1) * 4096 + 2 * tid;
            p0 = ldc_f2(p);        p1 = ldc_f2(p + 1024);
            p2 = ldc_f2(p + 2048); p3 = ldc_f2(p + 3072);
        }
        const unsigned w0 = act0 ? mk[(wv * 2) * 8 + c] : 0u;
        const unsigned w1 = act1 ? mk[(wv * 2 + 1) * 8 + c] : 0u;
        if (w0 | w1) {
#pragma unroll
            for (int bb = 0; bb < 32; ++bb) {  // unconditional sel-FMA: pipelined LDS reads
                const float2 v = *(const float2*)(cb + bb * HD + 2 * lane);
                const float s0 = (float)((w0 >> bb) & 1u);
                const float s1 = (float)((w1 >> bb) & 1u);
                m0.x = fmaf(s0, v.x, m0.x); m0.y = fmaf(s0, v.y, m0.y);
                m1.x = fmaf(s1, v.x, m1.x); m1.y = fmaf(s1, v.y, m1.y);
            }
        }
        if ((r0 >> 5) == c && r0 <= rmaxblk) h0  = *(const float2*)(cb + (r0 & 31) * HD + 2 * lane);
        if ((r1 >> 5) == c && r1 <= rmaxblk) h1v = *(const float2*)(cb + (r1 & 31) * HD + 2 * lane);
        __syncthreads();  // all waves done reading chunk c
        if (more) {
            float2* cb2 = (float2*)cb;
            cb2[tid] = p0; cb2[tid + 512] = p1; cb2[tid + 1024] = p2; cb2[tid + 1536] = p3;
            __syncthreads();
        }
    }
    if (r0 == tnew) {
        h0.x = z[2 * lane]     + pos_emb[r0 * HD + 2 * lane];
        h0.y = z[2 * lane + 1] + pos_emb[r0 * HD + 2 * lane + 1];
    }
    if (r1 == tnew) {
        h1v.x = z[2 * lane]     + pos_emb[r1 * HD + 2 * lane];
        h1v.y = z[2 * lane + 1] + pos_emb[r1 * HD + 2 * lane + 1];
    }

    // ST reuses CB (all reads done: last loop iter ended on __syncthreads)
    float* st = cb + wv * 512;
    st[4 * lane]     = h0.x;  st[4 * lane + 1] = m0.x;
    st[4 * lane + 2] = h0.y;  st[4 * lane + 3] = m0.y;
    st[256 + 4 * lane]     = h1v.x; st[256 + 4 * lane + 1] = m1.x;
    st[256 + 4 * lane + 2] = h1v.y; st[256 + 4 * lane + 3] = m1.y;
    __threadfence_block();

    const float bb_ = bias[ch * 64 + lane];
    float acc0 = bb_, acc1 = bb_;
    const float2* Wp = (const float2*)(lds + lofs) + lane;
    const float2* S0 = (const float2*)st;
    const float2* S1 = S0 + 128;
#pragma unroll 8
    for (int k = 0; k < HD; ++k) {
        const float2 w = Wp[k * 64];        // (Ws[k][c], Wn[k][c])
        const float2 a = S0[k], b2 = S1[k]; // (h[k], m[k]) broadcasts
        acc0 = fmaf(a.x,  w.x, fmaf(a.y,  w.y, acc0));
        acc1 = fmaf(b2.x, w.x, fmaf(b2.y, w.y, acc1));
    }
    if (r0 <= rmaxblk) stc_f(dst + r0 * HD + ch * 64 + lane, fmaxf(acc0, 0.f));
    if (r1 <= rmaxblk) stc_f(dst + r1 * HD + ch * 64 + lane, fmaxf(acc1, 0.f));
}

// MLP blocks, P1: ct[c] = cz[c] + h_s@Wm1[0:128] + pos_s@Wm1[384:512]  (block-local)
__device__ __forceinline__ void ct_calc(const float* hsP, const float* pos_emb,
                                        const float* Wm1, float* lds, int s)
{
    const int tid = threadIdx.x;
    float* hp = lds + HP_LDS;
    if (tid < 64) {
        const float2 v = ldc_f2(hsP + s * HD + 2 * tid);
        hp[2 * tid] = v.x; hp[2 * tid + 1] = v.y;
    } else if (tid < 128) {
        const int l2 = tid - 64;
        hp[128 + 2 * l2]     = pos_emb[s * HD + 2 * l2];
        hp[128 + 2 * l2 + 1] = pos_emb[s * HD + 2 * l2 + 1];
    }
    __syncthreads();
    const int c = tid & 255, half = tid >> 8;   // k-split across thread halves
    float acc = 0.f;
    const float* w = half ? (Wm1 + 384 * 256 + c) : (Wm1 + c);
    const float* hh = hp + half * 128;
#pragma unroll 4
    for (int k = 0; k < HD; ++k) acc = fmaf(hh[k], w[k * 256], acc);
    lds[HR_LDS + half * 256 + c] = acc;   // PART scratch (HR region, P1-only use)
    __syncthreads();
    if (tid < 256)
        lds[CT_LDS + tid] = lds[CZ_LDS + tid] + lds[HR_LDS + tid] + lds[HR_LDS + 256 + tid];
}

__device__ __forceinline__ void mlp_one(const float2 hv, int slot, int i, int s,
                                        const float* bm2, float* lds,
                                        const unsigned* gtl, int lane, int wv)
{
    unsigned* ancl = (unsigned*)(lds + ANC_LDS);
    float* hr = lds + HR_LDS + wv * 128;
    hr[2 * lane] = hv.x; hr[2 * lane + 1] = hv.y;
    __threadfence_block();
    float4 a = make_float4(0.f, 0.f, 0.f, 0.f);
    const float4* W4 = (const float4*)lds + lane;  // Wm1_mid[k*256 + 4*lane]
#pragma unroll 4
    for (int k = 0; k < HD; ++k) {
        const float hk = hr[k];
        const float4 w = W4[k * 64];
        a.x = fmaf(hk, w.x, a.x); a.y = fmaf(hk, w.y, a.y);
        a.z = fmaf(hk, w.z, a.z); a.w = fmaf(hk, w.w, a.w);
    }
    const float4 cc = *(const float4*)(lds + CT_LDS + 4 * lane);
    const float4 w2 = *(const float4*)(lds + W2_LDS + 4 * lane);
    float sd = fmaxf(a.x + cc.x, 0.f) * w2.x + fmaxf(a.y + cc.y, 0.f) * w2.y
             + fmaxf(a.z + cc.z, 0.f) * w2.z + fmaxf(a.w + cc.w, 0.f) * w2.w;
#pragma unroll
    for (int off = 32; off > 0; off >>= 1) sd += __shfl_xor(sd, off);
    if (lane == 0) {
        const float logit = sd + bm2[0];
        const float prob = 1.f / (1.f + expf(-logit));
        unsigned cnt = 0, has = 0;
#pragma unroll
        for (int w = 0; w < 8; ++w) {
            const unsigned av = ancl[slot * 8 + w];
            cnt += __popc(av);
            has |= av & gtl[w];
        }
        const float supp = ldexpf(1.f, -(int)cnt);  // 0.5^cnt exact incl. underflow
        const float adj = prob * supp;
        const unsigned gt = (gtl[i >> 5] >> (i & 31)) & 1u;
        const float lpv = gt ? logf(adj + 1e-12f) : logf(1.f - adj + 1e-12f);
        atomicAdd((float*)(lds + LP_LDS), lpv);
        if (has | gt) ancl[slot * 8 + (s >> 5)] |= (1u << (s & 31));  // anc[s][i]
    }
}

// MLP blocks, P2: candidates i0 = mb*16+wv, i1 = i0+8 (static ownership -> local ANC)
__device__ __forceinline__ void mlp_step(const float* hsP, const float* bm2,
                                         float* lds, int mb, int s)
{
    const int lane = threadIdx.x & 63, wv = threadIdx.x >> 6;
    const unsigned* gtl = (const unsigned*)(lds + TGTM_LDS) + s * 8;
    const int i0 = mb * 16 + wv, i1 = i0 + 8;
    float2 hva = make_float2(0.f, 0.f), hvb = hva;
    if (i0 < s) hva = ldc_f2(hsP + i0 * HD + 2 * lane);  // both loads in flight
    if (i1 < s) hvb = ldc_f2(hsP + i1 * HD + 2 * lane);
    if (i0 < s) mlp_one(hva, wv,     i0, s, bm2, lds, gtl, lane, wv);
    if (i1 < s) mlp_one(hvb, wv + 8, i1, s, bm2, lds, gtl, lane, wv);
}

extern "C" __global__ void __launch_bounds__(NTHR)
fused_gnn(const float* z, const int* targets, const float* pos_emb,
          const float* Ws1, const float* Wn1, const float* b1,
          const float* Ws2, const float* Wn2, const float* b2,
          const float* Wm1, const float* bm1, const float* Wm2, const float* bm2,
          const float* Wf, const float* bf, float* out, float* ws)
{
    __shared__ __align__(16) float lds[LDS_FLOATS];
    const int b = blockIdx.x;
    const int tid = threadIdx.x, lane = tid & 63, wv = tid >> 6;

    float* h1w = ws + H1_OFF;
    unsigned* flags = (unsigned*)(ws + FLAG_OFF);
    float* lp_out = out + NN * NN + NN * 16;

    const int ch = b & 1, rg = b >> 1;   // GNN blocks
    const int mb = b - GNN_NB;           // MLP blocks

    // ---- init ----
    if (b < GNN_NB) {
        for (int idx = tid; idx < 8192; idx += NTHR) {
            const int k = idx >> 6, c = idx & 63;
            lds[2 * idx]             = Ws1[k * HD + ch * 64 + c];
            lds[2 * idx + 1]         = Wn1[k * HD + ch * 64 + c];
            lds[16384 + 2 * idx]     = Ws2[k * HD + ch * 64 + c];
            lds[16384 + 2 * idx + 1] = Wn2[k * HD + ch * 64 + c];
        }
        // output 0: tgt, rows r = b*8+wv (host-read only; cached stores fine)
        {
            const int r = b * 8 + wv;
            const int4 tv = ((const int4*)(targets + r * NN))[lane];
            float4 ov;
            ov.x = (4 * lane     < r) ? (float)tv.x : 0.f;
            ov.y = (4 * lane + 1 < r) ? (float)tv.y : 0.f;
            ov.z = (4 * lane + 2 < r) ? (float)tv.z : 0.f;
            ov.w = (4 * lane + 3 < r) ? (float)tv.w : 0.f;
            ((float4*)(out + r * NN))[lane] = ov;
        }
        // own-row masks -> MK (wave wv: rows rg*16+wv, rg*16+wv+8)
        unsigned* mk = (unsigned*)(lds + MK_LDS);
#pragma unroll
        for (int rr = 0; rr < 2; ++rr) {
            const int r = rg * 16 + rr * 8 + wv;
#pragma unroll
            for (int q = 0; q < 4; ++q) {
                const int j = q * 64 + lane;
                const unsigned long long bm = __ballot(j < r && targets[r * NN + j] != 0);
                if (lane == 0) {
                    mk[(wv * 2 + rr) * 8 + 2 * q]     = (unsigned)bm;
                    mk[(wv * 2 + rr) * 8 + 2 * q + 1] = (unsigned)(bm >> 32);
                }
            }
        }
    } else {
        for (int idx = tid; idx < 32768; idx += NTHR)
            lds[idx] = Wm1[32768 + idx];             // Wm1 rows 128..255 (Hs block)
        if (tid < 256) {
            lds[W2_LDS + tid] = Wm2[tid];
            float acc = bm1[tid];
            for (int k = 0; k < HD; ++k) acc = fmaf(z[k], Wm1[(256 + k) * 256 + tid], acc);
            lds[CZ_LDS + tid] = acc;
        }
        if (tid < 128) ((unsigned*)(lds + ANC_LDS))[tid] = 0u;
        if (tid == 0) lds[LP_LDS] = 0.f;
        // full mask table: wave wv builds rows wv*32..wv*32+31
        {
            unsigned* tg = (unsigned*)(lds + TGTM_LDS);
            for (int rr = 0; rr < 32; ++rr) {
                const int r = wv * 32 + rr;
#pragma unroll
                for (int q = 0; q < 4; ++q) {
                    const int j = q * 64 + lane;
                    const unsigned long long bm = __ballot(j < r && targets[r * NN + j] != 0);
                    if (lane == 0) {
                        tg[r * 8 + 2 * q]     = (unsigned)bm;
                        tg[r * 8 + 2 * q + 1] = (unsigned)(bm >> 32);
                    }
                }
            }
        }
        // Hs0 init via sc1 stores: 16 blocks x 512 thr x 2 float2
#pragma unroll
        for (int q = 0; q < 2; ++q) {
            const int g = mb * 1024 + q * 512 + tid;  // float2 index
            float2 v = make_float2(0.f, 0.f);
            if (g < 64) v = make_float2(z[2 * g], z[2 * g + 1]);  // row 0 = h0 = z
            stc_f2(ws + HS0_OFF + 2 * g, v);
        }
        if (mb == 0 && tid == 0)
            __hip_atomic_store((unsigned*)lp_out, 0u, __ATOMIC_RELAXED,
                               __HIP_MEMORY_SCOPE_AGENT);
    }

    unsigned ph = 1;
    gridbar(flags, ph); ph++;

    // ---- t=1..255 decode; t=256 = final full-graph pass (+ MLP(255)) ----
    for (int t = 1; t <= 256; ++t) {
        const int s = t - 1;
        const float* hsP = ws + ((s & 1) ? HS1_OFF : HS0_OFF);
        float* hsN = ws + ((t & 1) ? HS1_OFF : HS0_OFF);
        const int rmax  = (t <= 255) ? t : 255;
        const int tgate = (t <= 255) ? t : 300;
        const int tnew  = (t <= 255) ? t : -1;

        // P1: layer1(t) [GNN]  ||  ct(t-1) [MLP]
        if (b < GNN_NB)
            layer_rows(hsP, h1w, b1, z, pos_emb, lds, 0, ch, rg, rmax, tgate, tnew);
        else if (t >= 2)
            ct_calc(hsP, pos_emb, Wm1, lds, s);
        gridbar(flags, ph); ph++;

        // P2: layer2(t) [GNN]  ||  MLP(t-1) [MLP]
        if (b < GNN_NB)
            layer_rows(h1w, hsN, b2, z, pos_emb, lds, 16384, ch, rg, rmax, tgate, -1);
        else if (t >= 2)
            mlp_step(hsP, bm2, lds, mb, s);
        gridbar(flags, ph); ph++;
    }

    // ---- epilogue ----
    if (b < GNN_NB) {
        // X_out = Hs_final @ Wf + bf ; final Hs in buffer 0 (t=256 even)
        const int r = b * 8 + wv;
        float* strow = lds + CB_LDS + wv * 128;
        const float2 hv = ldc_f2(ws + HS0_OFF + r * HD + 2 * lane);
        strow[2 * lane] = hv.x; strow[2 * lane + 1] = hv.y;
        __threadfence_block();
        const int f = lane & 15, kp = lane >> 4;
        float sacc = 0.f;
#pragma unroll
        for (int k = 0; k < 32; ++k)
            sacc = fmaf(strow[kp * 32 + k], Wf[(kp * 32 + k) * 16 + f], sacc);
        sacc += __shfl_xor(sacc, 16);
        sacc += __shfl_xor(sacc, 32);
        if (lane < 16) out[NN * NN + r * 16 + f] = sacc + bf[f];
    } else {
        __syncthreads();
        if (tid == 0) atomicAdd(lp_out, lds[LP_LDS]);
    }
}

extern "C" void kernel_launch(void* const* d_in, const int* in_sizes, int n_in,
                              void* d_out, int out_size, void* d_ws, size_t ws_size,
                              hipStream_t stream)
{
    const float* z       = (const float*)d_in[0];
    const int*   targets = (const int*)d_in[1];
    const float* pos_emb = (const float*)d_in[2];
    const float* Ws1     = (const float*)d_in[3];
    const float* Wn1     = (const float*)d_in[4];
    const float* b1      = (const float*)d_in[5];
    const float* Ws2     = (const float*)d_in[6];
    const float* Wn2     = (const float*)d_in[7];
    const float* b2      = (const float*)d_in[8];
    const float* Wm1     = (const float*)d_in[9];
    const float* bm1     = (const float*)d_in[10];
    const float* Wm2     = (const float*)d_in[11];
    const float* bm2     = (const float*)d_in[12];
    const float* Wf      = (const float*)d_in[13];
    const float* bf      = (const float*)d_in[14];
    float* out = (float*)d_out;
    float* ws  = (float*)d_ws;

    // zero the flag lines each call
    (void)hipMemsetAsync(ws + FLAG_OFF, 0, NBLK * 32 * sizeof(unsigned), stream);

    void* args[17] = {
        (void*)&z, (void*)&targets, (void*)&pos_emb,
        (void*)&Ws1, (void*)&Wn1, (void*)&b1,
        (void*)&Ws2, (void*)&Wn2, (void*)&b2,
        (void*)&Wm1, (void*)&bm1, (void*)&Wm2, (void*)&bm2,
        (void*)&Wf, (void*)&bf, (void*)&out, (void*)&ws
    };
    (void)hipLaunchCooperativeKernel((const void*)fused_gnn, dim3(NBLK), dim3(NTHR),
                                     args, 0, stream);
}

// Round 7
// 3412.830 us; speedup vs baseline: 6.0226x; 1.6020x over previous
//
#include <hip/hip_runtime.h>

#define NN 256
#define HD 128
#define GNN_NB 64
#define MLP_NB 64
#define NBLK 128
#define NTHR 512

// ws float offsets (cross-block-mutable data accessed ONLY via sc1 atomics)
#define HS0_OFF 0
#define HS1_OFF 32768
#define H1_OFF  65536
#define FLAG_OFF 98304   // 128 flags, stride 32 u32 (128B apart)

// GNN-block LDS layout (floats)
#define CB0_L 0          // chunk buf 0: 32 rows x 128
#define CB1_L 4096
#define STH_L 8192       // h rows [4][128]
#define STM_L 8704       // m rows [4][128]
#define PTA_L 9216       // [8][4][128] partials (m, then reused for outputs)
#define MK_L  13312      // 32 u32: 4 rows x 8 mask words
// MLP-block LDS layout (floats)
#define TGT_L 0          // 2048 u32 full mask table
#define PTM_L 2048       // [8][4][256] partials
#define PT3_L 10240      // [4][256]
#define HC_L  11264      // [4][128] candidate h rows
#define CT_L  11776      // [256]
#define CZ_L  12032      // [256]
#define W2_L  12288      // [256]
#define HP_L  12544      // [256] h_s | pos_s
#define PART_L 12800     // [512] ct partials
#define ANC_L 13312      // 32 u32
#define LP_L  13344
#define LDS_FLOATS 13360

// ---- device-coherent access (relaxed agent atomics -> sc1, bypass L1/L2) ----
__device__ __forceinline__ float2 ldc_f2(const float* p) {
    unsigned long long u = __hip_atomic_load((const unsigned long long*)p,
                                             __ATOMIC_RELAXED, __HIP_MEMORY_SCOPE_AGENT);
    float2 r;
    r.x = __uint_as_float((unsigned)u);
    r.y = __uint_as_float((unsigned)(u >> 32));
    return r;
}
__device__ __forceinline__ void stc_f(float* p, float v) {
    __hip_atomic_store((unsigned*)p, __float_as_uint(v),
                       __ATOMIC_RELAXED, __HIP_MEMORY_SCOPE_AGENT);
}

// block barrier that does NOT drain vmcnt (keeps sc1 prefetch in flight)
__device__ __forceinline__ void bar_lds() {
    asm volatile("s_waitcnt lgkmcnt(0)\n\ts_barrier" ::: "memory");
}

__device__ __forceinline__ void gridbar(unsigned* flags, unsigned ph) {
    __syncthreads();  // drains vmem -> all sc1 stores retired at coherence point
    if (threadIdx.x == 0)
        __hip_atomic_store(flags + blockIdx.x * 32, ph,
                           __ATOMIC_RELAXED, __HIP_MEMORY_SCOPE_AGENT);
    if (threadIdx.x < NBLK) {
        while (__hip_atomic_load(flags + threadIdx.x * 32,
                                 __ATOMIC_RELAXED, __HIP_MEMORY_SCOPE_AGENT) < ph)
            __builtin_amdgcn_s_sleep(1);
    }
    __syncthreads();
    asm volatile("" ::: "memory");
}

__device__ __forceinline__ void issue4(const float* src, int cofs, int tid, float2 p[4]) {
    const float* p0 = src + cofs * 4096 + 2 * tid;
    p[0] = ldc_f2(p0);        p[1] = ldc_f2(p0 + 1024);
    p[2] = ldc_f2(p0 + 2048); p[3] = ldc_f2(p0 + 3072);
}
__device__ __forceinline__ void write4(float* cb, int tid, const float2 p[4]) {
    float2* cb2 = (float2*)cb;
    cb2[tid] = p[0]; cb2[tid + 512] = p[1]; cb2[tid + 1024] = p[2]; cb2[tid + 1536] = p[3];
}

// One GNN layer for this block's 4 rows [4*rg, 4*rg+4), full 128 cols.
// Weights (this layer's k-slice) live in registers ws/wn.
__device__ __forceinline__ void layer_rows(const float* src, float* dst, const float* bias,
    const float* z, const float* pos_emb, float* lds,
    const float2 (&ws)[16], const float2 (&wn)[16],
    int rg, int rmax, int tgate, int tnew)
{
    const int tid = threadIdx.x, lane = tid & 63, wv = tid >> 6;
    const int R0 = rg * 4;
    const int rmaxblk = min(rmax, R0 + 3);
    const int nchunk = (rmaxblk >> 5) + 1;
    const unsigned* mk = (const unsigned*)(lds + MK_L);
    const int ks = wv * 16;

    float2 pA[4], pB[4];
    issue4(src, 0, tid, pA);
    if (nchunk > 1) issue4(src, 1, tid, pB);
    write4(lds + CB0_L, tid, pA);
    bar_lds();

    float2 m0 = make_float2(0.f, 0.f), m1 = m0, m2 = m0, m3 = m0;
    float2 h[4];
    h[0] = m0; h[1] = m0; h[2] = m0; h[3] = m0;
    const int hc = R0 >> 5;
    const int sb = wv * 4;

    for (int c = 0; c < nchunk; ++c) {
        const float* cb = lds + ((c & 1) ? CB1_L : CB0_L);
        if (c + 2 < nchunk) issue4(src, c + 2, tid, (c & 1) ? pB : pA);
        const unsigned mw0 = (R0     < tgate) ? mk[0 * 8 + c] : 0u;
        const unsigned mw1 = (R0 + 1 < tgate) ? mk[1 * 8 + c] : 0u;
        const unsigned mw2 = (R0 + 2 < tgate) ? mk[2 * 8 + c] : 0u;
        const unsigned mw3 = (R0 + 3 < tgate) ? mk[3 * 8 + c] : 0u;
#pragma unroll
        for (int ss = 0; ss < 4; ++ss) {
            const int bit = sb + ss;
            const float2 v = *(const float2*)(cb + bit * HD + 2 * lane);
            const float s0 = (float)((mw0 >> bit) & 1u);
            const float s1 = (float)((mw1 >> bit) & 1u);
            const float s2 = (float)((mw2 >> bit) & 1u);
            const float s3 = (float)((mw3 >> bit) & 1u);
            m0.x = fmaf(s0, v.x, m0.x); m0.y = fmaf(s0, v.y, m0.y);
            m1.x = fmaf(s1, v.x, m1.x); m1.y = fmaf(s1, v.y, m1.y);
            m2.x = fmaf(s2, v.x, m2.x); m2.y = fmaf(s2, v.y, m2.y);
            m3.x = fmaf(s3, v.x, m3.x); m3.y = fmaf(s3, v.y, m3.y);
        }
        if (wv == 0 && c == hc) {
#pragma unroll
            for (int dr = 0; dr < 4; ++dr)
                h[dr] = *(const float2*)(cb + ((R0 + dr) & 31) * HD + 2 * lane);
        }
        if (c + 1 < nchunk)
            write4(lds + (((c + 1) & 1) ? CB1_L : CB0_L), tid, ((c + 1) & 1) ? pB : pA);
        bar_lds();
    }

    // wave 0: tnew override + publish h rows
    if (wv == 0) {
#pragma unroll
        for (int dr = 0; dr < 4; ++dr) {
            if (R0 + dr == tnew) {
                h[dr].x = z[2 * lane]     + pos_emb[(R0 + dr) * HD + 2 * lane];
                h[dr].y = z[2 * lane + 1] + pos_emb[(R0 + dr) * HD + 2 * lane + 1];
            }
            *(float2*)(lds + STH_L + dr * HD + 2 * lane) = h[dr];
        }
    }
    // publish m partials
    *(float2*)(lds + PTA_L + (wv * 4 + 0) * HD + 2 * lane) = m0;
    *(float2*)(lds + PTA_L + (wv * 4 + 1) * HD + 2 * lane) = m1;
    *(float2*)(lds + PTA_L + (wv * 4 + 2) * HD + 2 * lane) = m2;
    *(float2*)(lds + PTA_L + (wv * 4 + 3) * HD + 2 * lane) = m3;
    bar_lds();

    // combine m partials -> STM
    {
        const int dr = tid >> 7, k = tid & 127;
        float s = 0.f;
#pragma unroll
        for (int w = 0; w < 8; ++w) s += lds[PTA_L + (w * 4 + dr) * HD + k];
        lds[STM_L + dr * HD + k] = s;
    }
    bar_lds();

    // matvec over this wave's 16-k slice, all 4 rows, cols (2*lane, 2*lane+1)
    float2 acc[4];
    acc[0] = make_float2(0.f, 0.f); acc[1] = acc[0]; acc[2] = acc[0]; acc[3] = acc[0];
#pragma unroll
    for (int kq = 0; kq < 8; ++kq) {
#pragma unroll
        for (int dr = 0; dr < 4; ++dr) {
            const float2 hp = *(const float2*)(lds + STH_L + dr * HD + ks + 2 * kq);
            const float2 mp = *(const float2*)(lds + STM_L + dr * HD + ks + 2 * kq);
            acc[dr].x = fmaf(hp.x, ws[2 * kq].x, fmaf(mp.x, wn[2 * kq].x, acc[dr].x));
            acc[dr].y = fmaf(hp.x, ws[2 * kq].y, fmaf(mp.x, wn[2 * kq].y, acc[dr].y));
            acc[dr].x = fmaf(hp.y, ws[2 * kq + 1].x, fmaf(mp.y, wn[2 * kq + 1].x, acc[dr].x));
            acc[dr].y = fmaf(hp.y, ws[2 * kq + 1].y, fmaf(mp.y, wn[2 * kq + 1].y, acc[dr].y));
        }
    }
    // publish output partials (reuse PTA region; prior reads completed at last bar)
#pragma unroll
    for (int dr = 0; dr < 4; ++dr)
        *(float2*)(lds + PTA_L + (wv * 4 + dr) * HD + 2 * lane) = acc[dr];
    bar_lds();

    // final combine + bias + relu + coherent store
    {
        const int dr = tid >> 7, c = tid & 127;
        float s = bias[c];
#pragma unroll
        for (int w = 0; w < 8; ++w) s += lds[PTA_L + (w * 4 + dr) * HD + c];
        const int R = R0 + dr;
        if (R <= rmaxblk) stc_f(dst + R * HD + c, fmaxf(s, 0.f));
    }
}

// MLP P1: ct[c] = cz[c] + h_s@Wm1[0:128] + pos_s@Wm1[384:512]
__device__ __forceinline__ void ct_calc(const float* hsP, const float* pos_emb,
                                        const float* Wm1, float* lds, int s)
{
    const int tid = threadIdx.x;
    if (tid < 64) {
        const float2 v = ldc_f2(hsP + s * HD + 2 * tid);
        lds[HP_L + 2 * tid] = v.x; lds[HP_L + 2 * tid + 1] = v.y;
    } else if (tid < 128) {
        const int l2 = tid - 64;
        lds[HP_L + 128 + 2 * l2]     = pos_emb[s * HD + 2 * l2];
        lds[HP_L + 128 + 2 * l2 + 1] = pos_emb[s * HD + 2 * l2 + 1];
    }
    __syncthreads();
    const int c = tid & 255, half = tid >> 8;
    float acc = 0.f;
    const float* w = half ? (Wm1 + 384 * 256 + c) : (Wm1 + c);
    const float* hh = lds + HP_L + half * 128;
#pragma unroll 4
    for (int k = 0; k < HD; ++k) acc = fmaf(hh[k], w[k * 256], acc);
    lds[PART_L + half * 256 + c] = acc;
    __syncthreads();
    if (tid < 256)
        lds[CT_L + tid] = lds[CZ_L + tid] + lds[PART_L + tid] + lds[PART_L + 256 + tid];
}

// MLP P2: 4 candidates i = 4*mb + ci (i < s); Wm1_mid k-slice in registers wm.
__device__ __forceinline__ void mlp_step(const float* hsP, const float* bm2,
                                         const float4 (&wm)[16], float* lds, int mb, int s)
{
    const int tid = threadIdx.x, lane = tid & 63, wv = tid >> 6;
    const int ks = wv * 16;
    if (wv < 4) {
        const int i = 4 * mb + wv;
        float2 v = make_float2(0.f, 0.f);
        if (i < s) v = ldc_f2(hsP + i * HD + 2 * lane);
        *(float2*)(lds + HC_L + wv * HD + 2 * lane) = v;
    }
    __syncthreads();
    float4 a0 = make_float4(0.f, 0.f, 0.f, 0.f), a1 = a0, a2 = a0, a3 = a0;
#pragma unroll
    for (int kk = 0; kk < 16; ++kk) {
        const int k = ks + kk;
        const float h0 = lds[HC_L + 0 * HD + k];
        const float h1 = lds[HC_L + 1 * HD + k];
        const float h2 = lds[HC_L + 2 * HD + k];
        const float h3 = lds[HC_L + 3 * HD + k];
        const float4 w = wm[kk];
        a0.x = fmaf(h0, w.x, a0.x); a0.y = fmaf(h0, w.y, a0.y);
        a0.z = fmaf(h0, w.z, a0.z); a0.w = fmaf(h0, w.w, a0.w);
        a1.x = fmaf(h1, w.x, a1.x); a1.y = fmaf(h1, w.y, a1.y);
        a1.z = fmaf(h1, w.z, a1.z); a1.w = fmaf(h1, w.w, a1.w);
        a2.x = fmaf(h2, w.x, a2.x); a2.y = fmaf(h2, w.y, a2.y);
        a2.z = fmaf(h2, w.z, a2.z); a2.w = fmaf(h2, w.w, a2.w);
        a3.x = fmaf(h3, w.x, a3.x); a3.y = fmaf(h3, w.y, a3.y);
        a3.z = fmaf(h3, w.z, a3.z); a3.w = fmaf(h3, w.w, a3.w);
    }
    *(float4*)(lds + PTM_L + (wv * 4 + 0) * 256 + 4 * lane) = a0;
    *(float4*)(lds + PTM_L + (wv * 4 + 1) * 256 + 4 * lane) = a1;
    *(float4*)(lds + PTM_L + (wv * 4 + 2) * 256 + 4 * lane) = a2;
    *(float4*)(lds + PTM_L + (wv * 4 + 3) * 256 + 4 * lane) = a3;
    __syncthreads();
    // combine k-slices, add ct, relu, scale by Wm2
    {
        const int c = tid & 255, ci2 = (tid >> 8) * 2;
#pragma unroll
        for (int q = 0; q < 2; ++q) {
            const int ci = ci2 + q;
            float v = lds[CT_L + c];
#pragma unroll
            for (int w = 0; w < 8; ++w) v += lds[PTM_L + (w * 4 + ci) * 256 + c];
            lds[PT3_L + ci * 256 + c] = fmaxf(v, 0.f) * lds[W2_L + c];
        }
    }
    __syncthreads();
    // per-candidate reduce + logp + ancestor update
    if (wv < 4) {
        const int ci = wv, i = 4 * mb + ci;
        if (i < s) {
            float sd = lds[PT3_L + ci * 256 + lane] + lds[PT3_L + ci * 256 + 64 + lane]
                     + lds[PT3_L + ci * 256 + 128 + lane] + lds[PT3_L + ci * 256 + 192 + lane];
#pragma unroll
            for (int off = 32; off > 0; off >>= 1) sd += __shfl_xor(sd, off);
            if (lane == 0) {
                const unsigned* gtl = (const unsigned*)(lds + TGT_L) + s * 8;
                unsigned* ancl = (unsigned*)(lds + ANC_L);
                const float logit = sd + bm2[0];
                const float prob = 1.f / (1.f + expf(-logit));
                unsigned cnt = 0, has = 0;
#pragma unroll
                for (int w = 0; w < 8; ++w) {
                    const unsigned av = ancl[ci * 8 + w];
                    cnt += __popc(av);
                    has |= av & gtl[w];
                }
                const float supp = ldexpf(1.f, -(int)cnt);  // 0.5^cnt exact
                const float adj = prob * supp;
                const unsigned gt = (gtl[i >> 5] >> (i & 31)) & 1u;
                const float lpv = gt ? logf(adj + 1e-12f) : logf(1.f - adj + 1e-12f);
                atomicAdd((float*)(lds + LP_L), lpv);
                if (has | gt) ancl[ci * 8 + (s >> 5)] |= (1u << (s & 31));
            }
        }
    }
}

extern "C" __global__ void __launch_bounds__(NTHR, 2)
fused_gnn(const float* z, const int* targets, const float* pos_emb,
          const float* Ws1, const float* Wn1, const float* b1,
          const float* Ws2, const float* Wn2, const float* b2,
          const float* Wm1, const float* bm1, const float* Wm2, const float* bm2,
          const float* Wf, const float* bf, float* out, float* ws)
{
    __shared__ __align__(16) float lds[LDS_FLOATS];
    const int b = blockIdx.x;
    const int tid = threadIdx.x, lane = tid & 63, wv = tid >> 6;

    float* h1w = ws + H1_OFF;
    unsigned* flags = (unsigned*)(ws + FLAG_OFF);
    float* lp_out = out + NN * NN + NN * 16;
    const int ks = wv * 16;

    if (b < GNN_NB) {
        // ---- GNN block: weights into registers (both layers) ----
        float2 ws1[16], wn1[16], ws2[16], wn2[16];
#pragma unroll
        for (int kk = 0; kk < 16; ++kk) {
            ws1[kk] = *(const float2*)(Ws1 + (ks + kk) * HD + 2 * lane);
            wn1[kk] = *(const float2*)(Wn1 + (ks + kk) * HD + 2 * lane);
            ws2[kk] = *(const float2*)(Ws2 + (ks + kk) * HD + 2 * lane);
            wn2[kk] = *(const float2*)(Wn2 + (ks + kk) * HD + 2 * lane);
        }
        // init: tgt output rows 4b..4b+3, own-row masks
        if (wv < 4) {
            const int r = b * 4 + wv;
            const int4 tv = ((const int4*)(targets + r * NN))[lane];
            float4 ov;
            ov.x = (4 * lane     < r) ? (float)tv.x : 0.f;
            ov.y = (4 * lane + 1 < r) ? (float)tv.y : 0.f;
            ov.z = (4 * lane + 2 < r) ? (float)tv.z : 0.f;
            ov.w = (4 * lane + 3 < r) ? (float)tv.w : 0.f;
            ((float4*)(out + r * NN))[lane] = ov;
            unsigned* mk = (unsigned*)(lds + MK_L);
#pragma unroll
            for (int q = 0; q < 4; ++q) {
                const int j = q * 64 + lane;
                const unsigned long long bm = __ballot(j < r && targets[r * NN + j] != 0);
                if (lane == 0) {
                    mk[wv * 8 + 2 * q]     = (unsigned)bm;
                    mk[wv * 8 + 2 * q + 1] = (unsigned)(bm >> 32);
                }
            }
        }

        unsigned ph = 1;
        gridbar(flags, ph); ph++;

        for (int t = 1; t <= 256; ++t) {
            const int s = t - 1;
            const float* hsP = ws + ((s & 1) ? HS1_OFF : HS0_OFF);
            float* hsN = ws + ((t & 1) ? HS1_OFF : HS0_OFF);
            const int rmax  = (t <= 255) ? t : 255;
            const int tgate = (t <= 255) ? t : 300;
            const int tnew  = (t <= 255) ? t : -1;
            if (b * 4 <= rmax)
                layer_rows(hsP, h1w, b1, z, pos_emb, lds, ws1, wn1, b, rmax, tgate, tnew);
            gridbar(flags, ph); ph++;
            if (b * 4 <= rmax)
                layer_rows(h1w, hsN, b2, z, pos_emb, lds, ws2, wn2, b, rmax, tgate, -1);
            gridbar(flags, ph); ph++;
        }

        // ---- X_out rows 4b..4b+3 (final Hs in buffer 0) ----
        if (wv < 4) {
            const int r = b * 4 + wv;
            const float2 hv = ldc_f2(ws + HS0_OFF + r * HD + 2 * lane);
            float* strow = lds + STH_L + wv * HD;
            strow[2 * lane] = hv.x; strow[2 * lane + 1] = hv.y;
            __threadfence_block();
            const int f = lane & 15, kp = lane >> 4;
            float sacc = 0.f;
#pragma unroll
            for (int k = 0; k < 32; ++k)
                sacc = fmaf(strow[kp * 32 + k], Wf[(kp * 32 + k) * 16 + f], sacc);
            sacc += __shfl_xor(sacc, 16);
            sacc += __shfl_xor(sacc, 32);
            if (lane < 16) out[NN * NN + r * 16 + f] = sacc + bf[f];
        }
    } else {
        // ---- MLP block: Wm1_mid k-slice into registers ----
        const int mb = b - GNN_NB;
        float4 wm[16];
#pragma unroll
        for (int kk = 0; kk < 16; ++kk)
            wm[kk] = *(const float4*)(Wm1 + (128 + ks + kk) * 256 + 4 * lane);
        // full mask table: wave wv builds rows wv*32..wv*32+31
        {
            unsigned* tg = (unsigned*)(lds + TGT_L);
            for (int rr = 0; rr < 32; ++rr) {
                const int r = wv * 32 + rr;
#pragma unroll
                for (int q = 0; q < 4; ++q) {
                    const int j = q * 64 + lane;
                    const unsigned long long bm = __ballot(j < r && targets[r * NN + j] != 0);
                    if (lane == 0) {
                        tg[r * 8 + 2 * q]     = (unsigned)bm;
                        tg[r * 8 + 2 * q + 1] = (unsigned)(bm >> 32);
                    }
                }
            }
        }
        if (tid < 256) {
            lds[W2_L + tid] = Wm2[tid];
            float acc = bm1[tid];
            for (int k = 0; k < HD; ++k) acc = fmaf(z[k], Wm1[(256 + k) * 256 + tid], acc);
            lds[CZ_L + tid] = acc;
        }
        if (tid < 32) ((unsigned*)(lds + ANC_L))[tid] = 0u;
        if (tid == 0) lds[LP_L] = 0.f;
        // Hs0 init: 64 blocks x 512 threads x 1 float
        {
            const int g = mb * 512 + tid;
            stc_f(ws + HS0_OFF + g, (g < HD) ? z[g] : 0.f);
        }
        if (mb == 0 && tid == 0)
            __hip_atomic_store((unsigned*)lp_out, 0u, __ATOMIC_RELAXED,
                               __HIP_MEMORY_SCOPE_AGENT);

        unsigned ph = 1;
        gridbar(flags, ph); ph++;

        for (int t = 1; t <= 256; ++t) {
            const int s = t - 1;
            const float* hsP = ws + ((s & 1) ? HS1_OFF : HS0_OFF);
            const bool act = (t >= 2) && (4 * mb < s);
            if (act) ct_calc(hsP, pos_emb, Wm1, lds, s);
            gridbar(flags, ph); ph++;
            if (act) mlp_step(hsP, bm2, wm, lds, mb, s);
            gridbar(flags, ph); ph++;
        }

        __syncthreads();
        if (tid == 0) atomicAdd(lp_out, lds[LP_L]);
    }
}

extern "C" void kernel_launch(void* const* d_in, const int* in_sizes, int n_in,
                              void* d_out, int out_size, void* d_ws, size_t ws_size,
                              hipStream_t stream)
{
    const float* z       = (const float*)d_in[0];
    const int*   targets = (const int*)d_in[1];
    const float* pos_emb = (const float*)d_in[2];
    const float* Ws1     = (const float*)d_in[3];
    const float* Wn1     = (const float*)d_in[4];
    const float* b1      = (const float*)d_in[5];
    const float* Ws2     = (const float*)d_in[6];
    const float* Wn2     = (const float*)d_in[7];
    const float* b2      = (const float*)d_in[8];
    const float* Wm1     = (const float*)d_in[9];
    const float* bm1     = (const float*)d_in[10];
    const float* Wm2     = (const float*)d_in[11];
    const float* bm2     = (const float*)d_in[12];
    const float* Wf      = (const float*)d_in[13];
    const float* bf      = (const float*)d_in[14];
    float* out = (float*)d_out;
    float* ws  = (float*)d_ws;

    (void)hipMemsetAsync(ws + FLAG_OFF, 0, NBLK * 32 * sizeof(unsigned), stream);

    void* args[17] = {
        (void*)&z, (void*)&targets, (void*)&pos_emb,
        (void*)&Ws1, (void*)&Wn1, (void*)&b1,
        (void*)&Ws2, (void*)&Wn2, (void*)&b2,
        (void*)&Wm1, (void*)&bm1, (void*)&Wm2, (void*)&bm2,
        (void*)&Wf, (void*)&bf, (void*)&out, (void*)&ws
    };
    (void)hipLaunchCooperativeKernel((const void*)fused_gnn, dim3(NBLK), dim3(NTHR),
                                     args, 0, stream);
}

// Round 8
// 2865.805 us; speedup vs baseline: 7.1722x; 1.1909x over previous
//
#include <hip/hip_runtime.h>

#define NN 256
#define HD 128
#define GNN_NB 64
#define MLP_NB 64
#define NBLK 128
#define NTHR 512

// ws float offsets (cross-block-mutable data accessed ONLY via sc1 atomics)
#define HS0_OFF 0
#define HS1_OFF 32768
#define H1_OFF  65536
#define GF_OFF  98304            // 64 gnn flags, stride 32 u32
#define MF_OFF  (98304 + 2048)   // 64 mlp flags, stride 32 u32

// GNN-block LDS (floats)
#define STH_L 0      // [4][128] own h rows (persist across phases)
#define STM_L 512    // [4][128] combined m rows
#define PT_L  1024   // [8][4][128] partials (gather m, then matvec outputs)
// MLP-block LDS (floats) — as R6
#define TGT_L 0
#define PTM_L 2048
#define PT3_L 10240
#define HC_L  11264
#define CT_L  11776
#define CZ_L  12032
#define W2_L  12288
#define HP_L  12544
#define PART_L 12800
#define ANC_L 13312
#define LP_L  13344
#define LDS_FLOATS 13360

// ---- device-coherent access (relaxed agent atomics -> sc1, bypass L1/L2) ----
__device__ __forceinline__ float2 ldc_f2(const float* p) {
    unsigned long long u = __hip_atomic_load((const unsigned long long*)p,
                                             __ATOMIC_RELAXED, __HIP_MEMORY_SCOPE_AGENT);
    float2 r;
    r.x = __uint_as_float((unsigned)u);
    r.y = __uint_as_float((unsigned)(u >> 32));
    return r;
}
__device__ __forceinline__ void stc_f(float* p, float v) {
    __hip_atomic_store((unsigned*)p, __float_as_uint(v),
                       __ATOMIC_RELAXED, __HIP_MEMORY_SCOPE_AGENT);
}

// block barrier that does NOT drain vmcnt
__device__ __forceinline__ void bar_lds() {
    asm volatile("s_waitcnt lgkmcnt(0)\n\ts_barrier" ::: "memory");
}

// GNN-only grid barrier; optionally also waits for MLP progress (buffer guard)
__device__ __forceinline__ void gnnbar(unsigned* gf, unsigned* mf, unsigned ph, int mlpmin) {
    __syncthreads();  // drains vmem -> sc1 stores retired at coherence point
    const int tid = threadIdx.x;
    if (tid == 0)
        __hip_atomic_store(gf + blockIdx.x * 32, ph,
                           __ATOMIC_RELAXED, __HIP_MEMORY_SCOPE_AGENT);
    if (tid < GNN_NB) {
        while (__hip_atomic_load(gf + tid * 32, __ATOMIC_RELAXED,
                                 __HIP_MEMORY_SCOPE_AGENT) < ph)
            __builtin_amdgcn_s_sleep(1);
    } else if (tid < 2 * GNN_NB && mlpmin > 0) {
        while (__hip_atomic_load(mf + (tid - GNN_NB) * 32, __ATOMIC_RELAXED,
                                 __HIP_MEMORY_SCOPE_AGENT) < (unsigned)mlpmin)
            __builtin_amdgcn_s_sleep(1);
    }
    __syncthreads();
    asm volatile("" ::: "memory");
}

#define ISS(i) \
    float2 va##i, vb##i, vc##i, vd##i; \
    if ((i) < nst) { \
        const float* p_ = gsrc + (i) * 32 * HD; \
        va##i = ldc_f2(p_);           vb##i = ldc_f2(p_ + HD); \
        vc##i = ldc_f2(p_ + 2 * HD);  vd##i = ldc_f2(p_ + 3 * HD); \
    }
#define ACCP(v, b) { \
    const float f0_ = (float)((s0 >> (b)) & 1u); \
    const float f1_ = (float)((s1 >> (b)) & 1u); \
    const float f2_ = (float)((s2 >> (b)) & 1u); \
    const float f3_ = (float)((s3 >> (b)) & 1u); \
    m0.x = fmaf(f0_, v.x, m0.x); m0.y = fmaf(f0_, v.y, m0.y); \
    m1.x = fmaf(f1_, v.x, m1.x); m1.y = fmaf(f1_, v.y, m1.y); \
    m2.x = fmaf(f2_, v.x, m2.x); m2.y = fmaf(f2_, v.y, m2.y); \
    m3.x = fmaf(f3_, v.x, m3.x); m3.y = fmaf(f3_, v.y, m3.y); }
#define CNS(i) if ((i) < nst) { ACCP(va##i, 4*(i)) ACCP(vb##i, 4*(i)+1) \
                                ACCP(vc##i, 4*(i)+2) ACCP(vd##i, 4*(i)+3) }

// One GNN layer for rows [R0, R0+3]. h rows live in STH (LDS), masks in scalar regs,
// gather loads sc1 direct-to-register (issued all up-front).
__device__ __forceinline__ void layer(const float* src, float* dst, const float* bias,
    const float* z, const float* pos_emb, float* lds,
    const float2 (&wsA)[16], const float2 (&wnA)[16],
    unsigned mk0, unsigned mk1, unsigned mk2, unsigned mk3,
    int R0, int rmax, int tgate, int tnew, int lane, int wv, int tid)
{
    const int rmaxblk = min(rmax, R0 + 3);
    const int nst = (rmaxblk + 31) >> 5;  // chunks covering parent rows 0..rmaxblk-1
    const unsigned s0 = (R0     < tgate) ? mk0 : 0u;
    const unsigned s1 = (R0 + 1 < tgate) ? mk1 : 0u;
    const unsigned s2 = (R0 + 2 < tgate) ? mk2 : 0u;
    const unsigned s3 = (R0 + 3 < tgate) ? mk3 : 0u;

    // new node: h row := z + pos_emb[tnew]
    if (tnew >= R0 && tnew < R0 + 4) {
        const int dr = tnew - R0;
        if (tid < HD) lds[STH_L + dr * HD + tid] = z[tid] + pos_emb[tnew * HD + tid];
    }

    // gather: wave wv owns src rows {32c + 4wv + ss}; all loads in flight at once
    const float* gsrc = src + wv * 4 * HD + 2 * lane;
    float2 m0 = make_float2(0.f, 0.f), m1 = m0, m2 = m0, m3 = m0;
    ISS(0) ISS(1) ISS(2) ISS(3) ISS(4) ISS(5) ISS(6) ISS(7)
    CNS(0) CNS(1) CNS(2) CNS(3) CNS(4) CNS(5) CNS(6) CNS(7)

    // publish m partials
    float* pt = lds + PT_L + (wv * 4) * HD + 2 * lane;
    *(float2*)pt = m0; *(float2*)(pt + HD) = m1;
    *(float2*)(pt + 2 * HD) = m2; *(float2*)(pt + 3 * HD) = m3;
    bar_lds();
    // combine partials -> STM
    {
        const int dr = tid >> 7, k = tid & 127;
        float s = 0.f;
#pragma unroll
        for (int w = 0; w < 8; ++w) s += lds[PT_L + (w * 4 + dr) * HD + k];
        lds[STM_L + dr * HD + k] = s;
    }
    bar_lds();
    // matvec over this wave's 16-k slice, 4 rows, cols (2*lane, 2*lane+1)
    const int ks = wv * 16;
    float2 a0 = make_float2(0.f, 0.f), a1 = a0, a2 = a0, a3 = a0;
#define MV(dr, areg) { \
    const float4 hp = *(const float4*)(lds + STH_L + (dr) * HD + ks + 4 * kq); \
    const float4 mp = *(const float4*)(lds + STM_L + (dr) * HD + ks + 4 * kq); \
    areg.x = fmaf(hp.x, wsA[4*kq].x,   fmaf(mp.x, wnA[4*kq].x,   areg.x)); \
    areg.y = fmaf(hp.x, wsA[4*kq].y,   fmaf(mp.x, wnA[4*kq].y,   areg.y)); \
    areg.x = fmaf(hp.y, wsA[4*kq+1].x, fmaf(mp.y, wnA[4*kq+1].x, areg.x)); \
    areg.y = fmaf(hp.y, wsA[4*kq+1].y, fmaf(mp.y, wnA[4*kq+1].y, areg.y)); \
    areg.x = fmaf(hp.z, wsA[4*kq+2].x, fmaf(mp.z, wnA[4*kq+2].x, areg.x)); \
    areg.y = fmaf(hp.z, wsA[4*kq+2].y, fmaf(mp.z, wnA[4*kq+2].y, areg.y)); \
    areg.x = fmaf(hp.w, wsA[4*kq+3].x, fmaf(mp.w, wnA[4*kq+3].x, areg.x)); \
    areg.y = fmaf(hp.w, wsA[4*kq+3].y, fmaf(mp.w, wnA[4*kq+3].y, areg.y)); }
#pragma unroll
    for (int kq = 0; kq < 4; ++kq) { MV(0, a0) MV(1, a1) MV(2, a2) MV(3, a3) }
#undef MV
    // publish matvec partials (reuse PT)
    *(float2*)pt = a0; *(float2*)(pt + HD) = a1;
    *(float2*)(pt + 2 * HD) = a2; *(float2*)(pt + 3 * HD) = a3;
    bar_lds();
    // final combine + bias + relu; keep in STH (next phase's h) + sc1 store
    {
        const int dr = tid >> 7, c = tid & 127;
        float o = bias[c];
#pragma unroll
        for (int w = 0; w < 8; ++w) o += lds[PT_L + (w * 4 + dr) * HD + c];
        o = fmaxf(o, 0.f);
        lds[STH_L + dr * HD + c] = o;
        const int R = R0 + dr;
        if (R <= rmaxblk) stc_f(dst + R * HD + c, o);
    }
}

// ---- MLP helpers (R6-proven numerics) ----
__device__ __forceinline__ void ct_calc(const float* hsP, const float* pos_emb,
                                        const float* Wm1, float* lds, int s)
{
    const int tid = threadIdx.x;
    if (tid < 64) {
        const float2 v = ldc_f2(hsP + s * HD + 2 * tid);
        lds[HP_L + 2 * tid] = v.x; lds[HP_L + 2 * tid + 1] = v.y;
    } else if (tid < 128) {
        const int l2 = tid - 64;
        lds[HP_L + 128 + 2 * l2]     = pos_emb[s * HD + 2 * l2];
        lds[HP_L + 128 + 2 * l2 + 1] = pos_emb[s * HD + 2 * l2 + 1];
    }
    __syncthreads();
    const int c = tid & 255, half = tid >> 8;
    float acc = 0.f;
    const float* w = half ? (Wm1 + 384 * 256 + c) : (Wm1 + c);
    const float* hh = lds + HP_L + half * 128;
#pragma unroll 4
    for (int k = 0; k < HD; ++k) acc = fmaf(hh[k], w[k * 256], acc);
    lds[PART_L + half * 256 + c] = acc;
    __syncthreads();
    if (tid < 256)
        lds[CT_L + tid] = lds[CZ_L + tid] + lds[PART_L + tid] + lds[PART_L + 256 + tid];
}

__device__ __forceinline__ void mlp_step(const float* hsP, const float* bm2,
                                         const float4 (&wm)[16], float* lds, int mb, int s)
{
    const int tid = threadIdx.x, lane = tid & 63, wv = tid >> 6;
    const int ks = wv * 16;
    if (wv < 4) {
        const int i = 4 * mb + wv;
        float2 v = make_float2(0.f, 0.f);
        if (i < s) v = ldc_f2(hsP + i * HD + 2 * lane);
        *(float2*)(lds + HC_L + wv * HD + 2 * lane) = v;
    }
    __syncthreads();
    float4 a0 = make_float4(0.f, 0.f, 0.f, 0.f), a1 = a0, a2 = a0, a3 = a0;
#pragma unroll
    for (int kk = 0; kk < 16; ++kk) {
        const int k = ks + kk;
        const float h0 = lds[HC_L + 0 * HD + k];
        const float h1 = lds[HC_L + 1 * HD + k];
        const float h2 = lds[HC_L + 2 * HD + k];
        const float h3 = lds[HC_L + 3 * HD + k];
        const float4 w = wm[kk];
        a0.x = fmaf(h0, w.x, a0.x); a0.y = fmaf(h0, w.y, a0.y);
        a0.z = fmaf(h0, w.z, a0.z); a0.w = fmaf(h0, w.w, a0.w);
        a1.x = fmaf(h1, w.x, a1.x); a1.y = fmaf(h1, w.y, a1.y);
        a1.z = fmaf(h1, w.z, a1.z); a1.w = fmaf(h1, w.w, a1.w);
        a2.x = fmaf(h2, w.x, a2.x); a2.y = fmaf(h2, w.y, a2.y);
        a2.z = fmaf(h2, w.z, a2.z); a2.w = fmaf(h2, w.w, a2.w);
        a3.x = fmaf(h3, w.x, a3.x); a3.y = fmaf(h3, w.y, a3.y);
        a3.z = fmaf(h3, w.z, a3.z); a3.w = fmaf(h3, w.w, a3.w);
    }
    *(float4*)(lds + PTM_L + (wv * 4 + 0) * 256 + 4 * lane) = a0;
    *(float4*)(lds + PTM_L + (wv * 4 + 1) * 256 + 4 * lane) = a1;
    *(float4*)(lds + PTM_L + (wv * 4 + 2) * 256 + 4 * lane) = a2;
    *(float4*)(lds + PTM_L + (wv * 4 + 3) * 256 + 4 * lane) = a3;
    __syncthreads();
    {
        const int c = tid & 255, ci2 = (tid >> 8) * 2;
#pragma unroll
        for (int q = 0; q < 2; ++q) {
            const int ci = ci2 + q;
            float v = lds[CT_L + c];
#pragma unroll
            for (int w = 0; w < 8; ++w) v += lds[PTM_L + (w * 4 + ci) * 256 + c];
            lds[PT3_L + ci * 256 + c] = fmaxf(v, 0.f) * lds[W2_L + c];
        }
    }
    __syncthreads();
    if (wv < 4) {
        const int ci = wv, i = 4 * mb + ci;
        if (i < s) {
            float sd = lds[PT3_L + ci * 256 + lane] + lds[PT3_L + ci * 256 + 64 + lane]
                     + lds[PT3_L + ci * 256 + 128 + lane] + lds[PT3_L + ci * 256 + 192 + lane];
#pragma unroll
            for (int off = 32; off > 0; off >>= 1) sd += __shfl_xor(sd, off);
            if (lane == 0) {
                const unsigned* gtl = (const unsigned*)(lds + TGT_L) + s * 8;
                unsigned* ancl = (unsigned*)(lds + ANC_L);
                const float logit = sd + bm2[0];
                const float prob = 1.f / (1.f + expf(-logit));
                unsigned cnt = 0, has = 0;
#pragma unroll
                for (int w = 0; w < 8; ++w) {
                    const unsigned av = ancl[ci * 8 + w];
                    cnt += __popc(av);
                    has |= av & gtl[w];
                }
                const float supp = ldexpf(1.f, -(int)cnt);  // 0.5^cnt exact
                const float adj = prob * supp;
                const unsigned gt = (gtl[i >> 5] >> (i & 31)) & 1u;
                const float lpv = gt ? logf(adj + 1e-12f) : logf(1.f - adj + 1e-12f);
                atomicAdd((float*)(lds + LP_L), lpv);
                if (has | gt) ancl[ci * 8 + (s >> 5)] |= (1u << (s & 31));
            }
        }
    }
}

extern "C" __global__ void __launch_bounds__(NTHR, 2)
fused_gnn(const float* z, const int* targets, const float* pos_emb,
          const float* Ws1, const float* Wn1, const float* b1,
          const float* Ws2, const float* Wn2, const float* b2,
          const float* Wm1, const float* bm1, const float* Wm2, const float* bm2,
          const float* Wf, const float* bf, float* out, float* ws)
{
    __shared__ __align__(16) float lds[LDS_FLOATS];
    const int b = blockIdx.x;
    const int tid = threadIdx.x, lane = tid & 63, wv = tid >> 6;

    float* h1w = ws + H1_OFF;
    unsigned* gf = (unsigned*)(ws + GF_OFF);
    unsigned* mf = (unsigned*)(ws + MF_OFF);
    float* lp_out = out + NN * NN + NN * 16;
    const int ks = wv * 16;

    if (b < GNN_NB) {
        const int R0 = b * 4;
        // weights into registers (both layers, k-slice per wave)
        float2 ws1[16], wn1[16], ws2[16], wn2[16];
#pragma unroll
        for (int kk = 0; kk < 16; ++kk) {
            ws1[kk] = *(const float2*)(Ws1 + (ks + kk) * HD + 2 * lane);
            wn1[kk] = *(const float2*)(Wn1 + (ks + kk) * HD + 2 * lane);
            ws2[kk] = *(const float2*)(Ws2 + (ks + kk) * HD + 2 * lane);
            wn2[kk] = *(const float2*)(Wn2 + (ks + kk) * HD + 2 * lane);
        }
        // per-wave static gather masks: bit b <-> src row (b>>2)*32 + wv*4 + (b&3)
        unsigned mk0, mk1, mk2, mk3;
        {
            const int srcl = (lane < 32) ? (((lane >> 2) << 5) + wv * 4 + (lane & 3)) : 0;
#define BALLOT_MK(dr, dst) { \
            const int r_ = R0 + (dr); \
            const bool p_ = (lane < 32) && (srcl < r_) && (targets[r_ * NN + srcl] != 0); \
            const unsigned long long bm_ = __ballot(p_); \
            dst = (unsigned)__builtin_amdgcn_readfirstlane((int)(unsigned)bm_); }
            BALLOT_MK(0, mk0) BALLOT_MK(1, mk1) BALLOT_MK(2, mk2) BALLOT_MK(3, mk3)
#undef BALLOT_MK
        }
        // init: STH (h rows), Hs0 global, tgt output
        lds[STH_L + tid] = (b == 0 && tid < HD) ? z[tid] : 0.f;  // 512 floats, 1/thread
        {
            const int dr = tid >> 7, c = tid & 127, r = R0 + dr;
            stc_f(ws + HS0_OFF + r * HD + c, (r == 0) ? z[c] : 0.f);
        }
        if (wv < 4) {
            const int r = R0 + wv;
            const int4 tv = ((const int4*)(targets + r * NN))[lane];
            float4 ov;
            ov.x = (4 * lane     < r) ? (float)tv.x : 0.f;
            ov.y = (4 * lane + 1 < r) ? (float)tv.y : 0.f;
            ov.z = (4 * lane + 2 < r) ? (float)tv.z : 0.f;
            ov.w = (4 * lane + 3 < r) ? (float)tv.w : 0.f;
            ((float4*)(out + r * NN))[lane] = ov;
        }

        gnnbar(gf, mf, 1u, 0);
        unsigned ph = 2;

        for (int t = 1; t <= 256; ++t) {
            const int s = t - 1;
            const float* hsP = ws + ((s & 1) ? HS1_OFF : HS0_OFF);
            float* hsN = ws + ((t & 1) ? HS1_OFF : HS0_OFF);
            const int rmax  = (t <= 255) ? t : 255;
            const int tgate = (t <= 255) ? t : 300;
            const int tnew  = (t <= 255) ? t : -1;

            if (R0 <= rmax)
                layer(hsP, h1w, b1, z, pos_emb, lds, ws1, wn1,
                      mk0, mk1, mk2, mk3, R0, rmax, tgate, tnew, lane, wv, tid);
            gnnbar(gf, mf, ph, (t >= 3) ? (t - 2) : 0); ph++;   // ph = 2t

            if (R0 <= rmax)
                layer(h1w, hsN, b2, z, pos_emb, lds, ws2, wn2,
                      mk0, mk1, mk2, mk3, R0, rmax, tgate, -1, lane, wv, tid);
            gnnbar(gf, mf, ph, 0); ph++;                         // ph = 2t+1
        }

        // X_out from STH (final Hs rows of this block)
        if (wv < 4) {
            const int r = R0 + wv;
            const float* strow = lds + STH_L + wv * HD;
            const int f = lane & 15, kp = lane >> 4;
            float sacc = 0.f;
#pragma unroll
            for (int k = 0; k < 32; ++k)
                sacc = fmaf(strow[kp * 32 + k], Wf[(kp * 32 + k) * 16 + f], sacc);
            sacc += __shfl_xor(sacc, 16);
            sacc += __shfl_xor(sacc, 32);
            if (lane < 16) out[NN * NN + r * 16 + f] = sacc + bf[f];
        }
    } else {
        // ---- MLP block: decoupled, runs 1-2 steps behind the GNN ----
        const int mb = b - GNN_NB;
        float4 wm[16];
#pragma unroll
        for (int kk = 0; kk < 16; ++kk)
            wm[kk] = *(const float4*)(Wm1 + (128 + ks + kk) * 256 + 4 * lane);
        {
            unsigned* tg = (unsigned*)(lds + TGT_L);
            for (int rr = 0; rr < 32; ++rr) {
                const int r = wv * 32 + rr;
#pragma unroll
                for (int q = 0; q < 4; ++q) {
                    const int j = q * 64 + lane;
                    const unsigned long long bm = __ballot(j < r && targets[r * NN + j] != 0);
                    if (lane == 0) {
                        tg[r * 8 + 2 * q]     = (unsigned)bm;
                        tg[r * 8 + 2 * q + 1] = (unsigned)(bm >> 32);
                    }
                }
            }
        }
        if (tid < 256) {
            lds[W2_L + tid] = Wm2[tid];
            float acc = bm1[tid];
            for (int k = 0; k < HD; ++k) acc = fmaf(z[k], Wm1[(256 + k) * 256 + tid], acc);
            lds[CZ_L + tid] = acc;
        }
        if (tid < 32) ((unsigned*)(lds + ANC_L))[tid] = 0u;
        if (tid == 0) lds[LP_L] = 0.f;
        if (mb == 0 && tid == 0)
            __hip_atomic_store((unsigned*)lp_out, 0u, __ATOMIC_RELAXED,
                               __HIP_MEMORY_SCOPE_AGENT);

        for (int s = 1; s <= 255; ++s) {
            // wait: Hs(s) complete <=> all gnn flags >= 2s+1
            if (tid < GNN_NB) {
                const unsigned tgt_ph = 2u * (unsigned)s + 1u;
                while (__hip_atomic_load(gf + tid * 32, __ATOMIC_RELAXED,
                                         __HIP_MEMORY_SCOPE_AGENT) < tgt_ph)
                    __builtin_amdgcn_s_sleep(1);
            }
            __syncthreads();
            const float* hsP = ws + ((s & 1) ? HS1_OFF : HS0_OFF);
            if (4 * mb < s) {
                ct_calc(hsP, pos_emb, Wm1, lds, s);
                __syncthreads();
                mlp_step(hsP, bm2, wm, lds, mb, s);
            }
            __syncthreads();  // all reads of Hs(s) done (vmcnt drained per wave)
            if (tid == 0)
                __hip_atomic_store(mf + mb * 32, (unsigned)s,
                                   __ATOMIC_RELAXED, __HIP_MEMORY_SCOPE_AGENT);
        }
        __syncthreads();
        if (tid == 0) atomicAdd(lp_out, lds[LP_L]);
    }
}

extern "C" void kernel_launch(void* const* d_in, const int* in_sizes, int n_in,
                              void* d_out, int out_size, void* d_ws, size_t ws_size,
                              hipStream_t stream)
{
    const float* z       = (const float*)d_in[0];
    const int*   targets = (const int*)d_in[1];
    const float* pos_emb = (const float*)d_in[2];
    const float* Ws1     = (const float*)d_in[3];
    const float* Wn1     = (const float*)d_in[4];
    const float* b1      = (const float*)d_in[5];
    const float* Ws2     = (const float*)d_in[6];
    const float* Wn2     = (const float*)d_in[7];
    const float* b2      = (const float*)d_in[8];
    const float* Wm1     = (const float*)d_in[9];
    const float* bm1     = (const float*)d_in[10];
    const float* Wm2     = (const float*)d_in[11];
    const float* bm2     = (const float*)d_in[12];
    const float* Wf      = (const float*)d_in[13];
    const float* bf      = (const float*)d_in[14];
    float* out = (float*)d_out;
    float* ws  = (float*)d_ws;

    // zero gnn + mlp flag lines each call
    (void)hipMemsetAsync(ws + GF_OFF, 0, 2 * GNN_NB * 32 * sizeof(unsigned), stream);

    void* args[17] = {
        (void*)&z, (void*)&targets, (void*)&pos_emb,
        (void*)&Ws1, (void*)&Wn1, (void*)&b1,
        (void*)&Ws2, (void*)&Wn2, (void*)&b2,
        (void*)&Wm1, (void*)&bm1, (void*)&Wm2, (void*)&bm2,
        (void*)&Wf, (void*)&bf, (void*)&out, (void*)&ws
    };
    (void)hipLaunchCooperativeKernel((const void*)fused_gnn, dim3(NBLK), dim3(NTHR),
                                     args, 0, stream);
}